// Round 15
// baseline (281.690 us; speedup 1.0000x reference)
//
#include <hip/hip_runtime.h>

typedef unsigned short ushort_t;
typedef unsigned long long u64_t;
typedef __attribute__((ext_vector_type(8))) short v8bf;
typedef __attribute__((ext_vector_type(8))) unsigned short v8us;
typedef __attribute__((ext_vector_type(4))) float v4f;

#define BROWS 4096
#define DIMK 256
#define QN 32768
#define EXPSCALE 14.426950408889634f   // 10 * log2(e)

__device__ __forceinline__ ushort_t f2bf(float f) {
    unsigned u = __float_as_uint(f);
    return (ushort_t)((u + 0x7FFFu + ((u >> 16) & 1u)) >> 16);   // RNE
}
__device__ __forceinline__ u64_t shfl_xor_u64(u64_t v, int off) {
    unsigned lo = (unsigned)(v & 0xFFFFFFFFull);
    unsigned hi = (unsigned)(v >> 32);
    lo = (unsigned)__shfl_xor((int)lo, off, 64);
    hi = (unsigned)__shfl_xor((int)hi, off, 64);
    return ((u64_t)hi << 32) | (u64_t)lo;
}
#define GLOAD(g, l_) __builtin_amdgcn_global_load_lds(                         \
    (const __attribute__((address_space(1))) void*)(g),                        \
    (__attribute__((address_space(3))) void*)(l_), 16, 0, 0)

// ---- bf16 conversion of the queue ----
__global__ __launch_bounds__(256) void conv_bf16(const float* __restrict__ in,
                                                 ushort_t* __restrict__ out) {
    const size_t i = ((size_t)blockIdx.x * 256 + threadIdx.x) * 8;
    float4 x = *(const float4*)&in[i];
    float4 y = *(const float4*)&in[i + 4];
    v8us o;
    o[0] = f2bf(x.x); o[1] = f2bf(x.y); o[2] = f2bf(x.z); o[3] = f2bf(x.w);
    o[4] = f2bf(y.x); o[5] = f2bf(y.y); o[6] = f2bf(y.z); o[7] = f2bf(y.w);
    *(v8us*)&out[i] = o;
}

// ---- fused two-layer projection + L2 norm (16 rows/block, grid.y = f1/f2) ----
__global__ __launch_bounds__(256) void proj_fused(const float* __restrict__ F1,
                                                  const float* __restrict__ F2,
                                                  const float* __restrict__ W1,
                                                  const float* __restrict__ b1,
                                                  const float* __restrict__ W2,
                                                  const float* __restrict__ b2,
                                                  ushort_t* __restrict__ P) {
    __shared__ float fr[16][256];
    __shared__ float hr[16][256];
    __shared__ float partial[4][16];
    const float* F = blockIdx.y ? F2 : F1;
    ushort_t* Po = P + (size_t)blockIdx.y * BROWS * DIMK;
    const int r0 = blockIdx.x << 4, j = threadIdx.x;
    const int w = j >> 6, l = j & 63;
#pragma unroll
    for (int r = 0; r < 16; ++r) fr[r][j] = F[(size_t)(r0 + r) * DIMK + j];
    __syncthreads();
    float acc[16];
    {
        const float bj = b1[j];
#pragma unroll
        for (int r = 0; r < 16; ++r) acc[r] = bj;
        for (int k = 0; k < DIMK; k += 4) {
            const float w0 = W1[(k + 0) * DIMK + j];
            const float w1 = W1[(k + 1) * DIMK + j];
            const float w2 = W1[(k + 2) * DIMK + j];
            const float w3 = W1[(k + 3) * DIMK + j];
#pragma unroll
            for (int r = 0; r < 16; ++r) {
                float4 f = *(const float4*)&fr[r][k];
                acc[r] = fmaf(f.x, w0, acc[r]);
                acc[r] = fmaf(f.y, w1, acc[r]);
                acc[r] = fmaf(f.z, w2, acc[r]);
                acc[r] = fmaf(f.w, w3, acc[r]);
            }
        }
#pragma unroll
        for (int r = 0; r < 16; ++r) hr[r][j] = acc[r] > 0.f ? acc[r] : 0.f;
    }
    __syncthreads();
    {
        const float bj = b2[j];
#pragma unroll
        for (int r = 0; r < 16; ++r) acc[r] = bj;
        for (int k = 0; k < DIMK; k += 4) {
            const float w0 = W2[(k + 0) * DIMK + j];
            const float w1 = W2[(k + 1) * DIMK + j];
            const float w2 = W2[(k + 2) * DIMK + j];
            const float w3 = W2[(k + 3) * DIMK + j];
#pragma unroll
            for (int r = 0; r < 16; ++r) {
                float4 f = *(const float4*)&hr[r][k];
                acc[r] = fmaf(f.x, w0, acc[r]);
                acc[r] = fmaf(f.y, w1, acc[r]);
                acc[r] = fmaf(f.z, w2, acc[r]);
                acc[r] = fmaf(f.w, w3, acc[r]);
            }
        }
    }
#pragma unroll
    for (int r = 0; r < 16; ++r) {
        float s = acc[r] * acc[r];
        s += __shfl_xor(s, 1);  s += __shfl_xor(s, 2);
        s += __shfl_xor(s, 4);  s += __shfl_xor(s, 8);
        s += __shfl_xor(s, 16); s += __shfl_xor(s, 32);
        if (l == 0) partial[w][r] = s;
    }
    __syncthreads();
#pragma unroll
    for (int r = 0; r < 16; ++r) {
        const float tot = partial[0][r] + partial[1][r] + partial[2][r] + partial[3][r];
        const float inv = 1.f / fmaxf(sqrtf(tot), 1e-12f);
        Po[(size_t)(r0 + r) * DIMK + j] = f2bf(acc[r] * inv);
    }
}

// ---- stage a 128-row x 256-k bf16 panel into 64KB LDS (512 threads, 8/thread).
// Global source pre-swizzled: 16B slot s of row r holds octet (s&~7)|((s&7)^(r&7)).
__device__ __forceinline__ void stage_panel(const ushort_t* __restrict__ M, int grow0,
                                            ushort_t* lds, int w, int l) {
#pragma unroll
    for (int j = 0; j < 8; ++j) {
        const int seg = (j << 3) + w;              // 64 segs of 1KB
        const int row = (seg << 1) + (l >> 5);     // 512B rows
        const int s = l & 31;
        const int oct = (s & ~7) | ((s & 7) ^ (row & 7));
        GLOAD(&M[(size_t)(grow0 + row) * DIMK + (oct << 3)], lds + (seg << 9));
    }
}

// ---- stage a 512-col x 32-k B tile (32KB, 64B rows; 512 threads, 4/thread).
// Pre-swizzled source: phys 16B slot s of row r holds logical octet s ^ ((r>>1)&3).
__device__ __forceinline__ void stage_b(const ushort_t* __restrict__ B, int col0,
                                        int kelem, ushort_t* dst, int w, int l) {
#pragma unroll
    for (int j = 0; j < 4; ++j) {
        const int seg = (j << 3) + w;                 // 32 segs of 1KB (16 rows)
        const int row = (seg << 4) + (l >> 2);
        const int oct = (l & 3) ^ ((l >> 3) & 3);     // == (l&3) ^ ((row>>1)&3)
        GLOAD(&B[(size_t)(col0 + row) * DIMK + kelem + (oct << 3)], dst + (seg << 9));
    }
}

// ---- persistent single-block-per-CU GEMM, m97 single-barrier schedule.
// 512 threads = 8 waves (2M x 4N); block tile 128 rows x 512 cols; wave tile
// 64x128 (acc 4x8 = 128 VGPR). A panel hoisted to LDS once; B tiles (32KB)
// double-buffered; phase p: issue stage(p+1), compute from buf[p&1], ONE
// __syncthreads. LDS 128KB -> 1 block/CU.
// __launch_bounds__(512, 2): 8 waves/block = 2 waves/EU natively; declaring 2
// raises the VGPR cap to 256/wave. R14 omitted it -> allocator capped 128 ->
// acc spilled (WRITE_SIZE 66MB). Spill tripwire: WRITE_SIZE >> KB.
// MODE 0: fused argmax, 256 blocks (=CUs), NT=16; XCD-pinned L2 decode (R9).
// MODE 1: exp-sums + diag, 256 blocks, NT=2, plain-store partial strips.
template <int MODE, int NT>
__global__ __launch_bounds__(512, 2) void nn_lse(const ushort_t* __restrict__ Abase,
                                                 const ushort_t* __restrict__ Bbase,
                                                 u64_t* __restrict__ packed,
                                                 float* __restrict__ srp,
                                                 float* __restrict__ scp,
                                                 float* __restrict__ diag) {
    __shared__ __align__(16) ushort_t Alds[128 * 256];   // 64 KB, staged once
    __shared__ __align__(16) ushort_t Bs[2][512 * 32];   // 2 x 32 KB
    const int tid = threadIdx.x;
    const int w = tid >> 6, l = tid & 63;
    const int wr = w >> 2, wc = w & 3;   // 2M x 4N waves; wave tile 64x128
    constexpr int NP = NT * 8;

    int arow0, colbase, rowblk = 0, colstrip = 0, z = 0;
    const ushort_t* A; const ushort_t* B;
    u64_t* pk_out = nullptr;
    float* dg = nullptr;
    if (MODE == 0) {
        const int bid = blockIdx.x;                // 256 blocks = 1 per CU
        const int xcd = bid & 7, i = bid >> 3;     // i in 0..31
        const int half = xcd & 1;
        const int pairgrp = xcd >> 1;              // owns 8192 cols
        arow0 = i << 7;                            // 32 row-blocks of 128
        colbase = pairgrp << 13;
        A = Abase + (size_t)half * BROWS * DIMK;
        B = Bbase;
        pk_out = packed + (size_t)half * BROWS;
    } else {
        z = blockIdx.x & 1;
        const int i = blockIdx.x >> 1;             // 0..127
        rowblk = i & 31;
        colstrip = i >> 5;                         // 0..3, 1024 cols each
        arow0 = rowblk << 7;
        colbase = colstrip << 10;
        A = Abase + (size_t)z * BROWS * DIMK;
        B = Bbase + (size_t)(1 - z) * BROWS * DIMK;
        dg = diag + (size_t)z * BROWS;
    }

    // prologue: A panel + first B tile, one drain
    stage_panel(A, arow0, (ushort_t*)Alds, w, l);
    stage_b(B, colbase, 0, &Bs[0][0], w, l);
    __syncthreads();

    unsigned best[4][4];
    float rsum[4][4];
#pragma unroll
    for (int a = 0; a < 4; ++a)
#pragma unroll
        for (int r = 0; r < 4; ++r) { best[a][r] = 0u; rsum[a][r] = 0.f; }

    for (int t = 0; t < NT; ++t) {
        v4f acc[4][8];
        const float cinit = (MODE == 0) ? 2.0f : 0.0f;   // +2 -> positive, uint-monotone
#pragma unroll
        for (int a = 0; a < 4; ++a)
#pragma unroll
            for (int b = 0; b < 8; ++b) acc[a][b] = (v4f){cinit, cinit, cinit, cinit};

#pragma unroll
        for (int k0 = 0; k0 < 8; ++k0) {          // K-phases of 32
            const int p = (t << 3) + k0;
            if (p + 1 < NP) {                      // stage next phase's B tile
                const int tn = (p + 1) >> 3, kn = (p + 1) & 7;
                stage_b(B, colbase + (tn << 9), kn << 5, &Bs[(p + 1) & 1][0], w, l);
            }
            const ushort_t* bufr = &Bs[p & 1][0];
            const int lo = l >> 4;                 // 0..3
            v8bf av[4], bv[8];
#pragma unroll
            for (int mi = 0; mi < 4; ++mi) {
                const int row = (wr << 6) + (mi << 4) + (l & 15);
                const int phys = ((k0 >> 1) << 3) | ((((k0 & 1) << 2) + lo) ^ (row & 7));
                av[mi] = *(const v8bf*)&Alds[(row << 8) + (phys << 3)];
            }
#pragma unroll
            for (int nj = 0; nj < 8; ++nj) {
                const int row = (wc << 7) + (nj << 4) + (l & 15);
                const int phys = lo ^ ((row >> 1) & 3);
                bv[nj] = *(const v8bf*)&bufr[(row << 5) + (phys << 3)];
            }
#pragma unroll
            for (int mi = 0; mi < 4; ++mi)
#pragma unroll
                for (int nj = 0; nj < 8; ++nj)
                    acc[mi][nj] = __builtin_amdgcn_mfma_f32_16x16x32_bf16(
                        av[mi], bv[nj], acc[mi][nj], 0, 0, 0);
            __syncthreads();   // drains own stage(p+1); all waves done with bufr
        }

        if (MODE == 0) {
            // running argmax: (bits(v+2) & 0xFFFFFF80) | (t<<3) | nj, uint-max
#pragma unroll
            for (int mi = 0; mi < 4; ++mi)
#pragma unroll
                for (int r = 0; r < 4; ++r) {
                    unsigned m = (__float_as_uint(acc[mi][0][r]) & 0xFFFFFF80u) |
                                 ((unsigned)t << 3);
#pragma unroll
                    for (int nj = 1; nj < 8; ++nj) {
                        unsigned c = (__float_as_uint(acc[mi][nj][r]) & 0xFFFFFF80u) |
                                     ((unsigned)t << 3) | (unsigned)nj;
                        m = c > m ? c : m;
                    }
                    if (m > best[mi][r]) best[mi][r] = m;
                }
        } else {
            const int cb = colbase + (t << 9);
#pragma unroll
            for (int mi = 0; mi < 4; ++mi)
#pragma unroll
                for (int nj = 0; nj < 8; ++nj) {
                    const int gr16 = arow0 + (wr << 6) + (mi << 4);
                    const int gc16 = cb + (wc << 7) + (nj << 4);
                    if (gr16 == gc16) {
#pragma unroll
                        for (int r = 0; r < 4; ++r) {
                            const int rr = ((l >> 4) << 2) + r;
                            if ((l & 15) == rr) dg[gr16 + rr] = acc[mi][nj][r] * 10.0f;
                        }
                    }
                }
#pragma unroll
            for (int mi = 0; mi < 4; ++mi)
#pragma unroll
                for (int nj = 0; nj < 8; ++nj) {
                    v4f tv = acc[mi][nj];
                    tv[0] = exp2f(tv[0] * EXPSCALE);
                    tv[1] = exp2f(tv[1] * EXPSCALE);
                    tv[2] = exp2f(tv[2] * EXPSCALE);
                    tv[3] = exp2f(tv[3] * EXPSCALE);
                    acc[mi][nj] = tv;
                }
#pragma unroll
            for (int mi = 0; mi < 4; ++mi)
#pragma unroll
                for (int r = 0; r < 4; ++r) {
                    float s = 0.f;
#pragma unroll
                    for (int nj = 0; nj < 8; ++nj) s += acc[mi][nj][r];
                    rsum[mi][r] += s;
                }
            // col partials: unique strip (z,rowblk,wr); plain stores
#pragma unroll
            for (int nj = 0; nj < 8; ++nj) {
                float s = 0.f;
#pragma unroll
                for (int mi = 0; mi < 4; ++mi)
#pragma unroll
                    for (int r = 0; r < 4; ++r) s += acc[mi][nj][r];
                s += __shfl_xor(s, 16); s += __shfl_xor(s, 32);
                if (l < 16)
                    scp[((size_t)(z << 6) + (rowblk << 1) + wr) * BROWS +
                        cb + (wc << 7) + (nj << 4) + l] = s;
            }
        }
    }

    if (MODE == 0) {
#pragma unroll
        for (int mi = 0; mi < 4; ++mi)
#pragma unroll
            for (int r = 0; r < 4; ++r) {
                const unsigned wb = best[mi][r];
                const unsigned col = (unsigned)(colbase + (int)(((wb >> 3) & 15u) << 9) +
                                                (wc << 7) + (int)((wb & 7u) << 4)) + (l & 15);
                u64_t pk = ((u64_t)wb << 32) | (u64_t)(0xFFFFFFFFu - col);
#pragma unroll
                for (int off = 1; off < 16; off <<= 1) {
                    u64_t o = shfl_xor_u64(pk, off);
                    if (o > pk) pk = o;
                }
                if ((l & 15) == 0)
                    atomicMax(&pk_out[arow0 + (wr << 6) + (mi << 4) + ((l >> 4) << 2) + r], pk);
            }
    } else {
        // row partials: unique strip (z, colstrip, wc); plain stores
#pragma unroll
        for (int mi = 0; mi < 4; ++mi)
#pragma unroll
            for (int r = 0; r < 4; ++r) {
                float s = rsum[mi][r];
                s += __shfl_xor(s, 1); s += __shfl_xor(s, 2);
                s += __shfl_xor(s, 4); s += __shfl_xor(s, 8);
                if ((l & 15) == 0)
                    srp[((size_t)(z << 4) + (colstrip << 2) + wc) * BROWS +
                        arow0 + (wr << 6) + (mi << 4) + ((l >> 4) << 2) + r] = s;
            }
    }
}

// ---- fold partial strips into sums[4][BROWS] ----
__global__ __launch_bounds__(256) void reduce_sums(const float* __restrict__ srp,
                                                   const float* __restrict__ scp,
                                                   float* __restrict__ sums) {
    const int idx = blockIdx.x * 256 + threadIdx.x;   // 8192
    const int z = idx >> 12, row = idx & 4095;
    float a = 0.f, b = 0.f;
#pragma unroll 4
    for (int s = 0; s < 16; ++s) a += srp[((size_t)(z << 4) + s) * BROWS + row];
#pragma unroll 4
    for (int s = 0; s < 64; ++s) b += scp[((size_t)(z << 6) + s) * BROWS + row];
    sums[(size_t)(2 * z) * BROWS + row] = a;
    sums[(size_t)(2 * z + 1) * BROWS + row] = b;
}

// ---- gather nn rows: 8 rows/block-iter, 16B/lane ----
__global__ __launch_bounds__(256) void gather_bf(const u64_t* __restrict__ packed,
                                                 const ushort_t* __restrict__ qb,
                                                 ushort_t* __restrict__ nn) {
    const int r8 = threadIdx.x >> 5;   // 0..7
    const int c = threadIdx.x & 31;    // 32 chunks of 8 ushorts
    for (int base = blockIdx.x * 8; base < 2 * BROWS; base += (int)gridDim.x * 8) {
        const int i = base + r8;
        const unsigned idx = 0xFFFFFFFFu - (unsigned)(packed[i] & 0xFFFFFFFFull);
        *(v8us*)&nn[(size_t)i * DIMK + (c << 3)] =
            *(const v8us*)&qb[(size_t)idx * DIMK + (c << 3)];
    }
}

__global__ __launch_bounds__(256) void final_loss(const float* __restrict__ d1,
                                                  const float* __restrict__ d2,
                                                  const float* __restrict__ sr1,
                                                  const float* __restrict__ sc1,
                                                  const float* __restrict__ sr2,
                                                  const float* __restrict__ sc2,
                                                  float* __restrict__ out) {
    __shared__ float red[256];
    const int t = threadIdx.x;
    float acc = 0.f;
    for (int i = t; i < BROWS; i += 256) {
        acc += 2.f * (d1[i] + d2[i]) - logf(sr1[i]) - logf(sc1[i]) - logf(sr2[i]) - logf(sc2[i]);
    }
    red[t] = acc;
    __syncthreads();
    for (int s = 128; s > 0; s >>= 1) {
        if (t < s) red[t] += red[t + s];
        __syncthreads();
    }
    if (t == 0) out[0] = -red[0] / (4.0f * (float)BROWS);
}

extern "C" void kernel_launch(void* const* d_in, const int* in_sizes, int n_in,
                              void* d_out, int out_size, void* d_ws, size_t ws_size,
                              hipStream_t stream) {
    const float* f1 = (const float*)d_in[0];
    const float* f2 = (const float*)d_in[1];
    const float* W1 = (const float*)d_in[2];
    const float* b1 = (const float*)d_in[3];
    const float* W2 = (const float*)d_in[4];
    const float* b2 = (const float*)d_in[5];
    const float* queue = (const float*)d_in[6];
    float* out = (float*)d_out;

    char* ws = (char*)d_ws;
    ushort_t* pcat  = (ushort_t*)(ws + (8ull << 20));      // 4 MB: p1 | p2
    ushort_t* nncat = (ushort_t*)(ws + (12ull << 20));     // 4 MB: nn1 | nn2
    ushort_t* qb    = (ushort_t*)(ws + (16ull << 20));     // 16 MB
    u64_t* packed   = (u64_t*)(ws + (32ull << 20));        // 64 KB (8192 rows)
    float* sums     = (float*)(ws + (32ull << 20) + (64ull << 10));    // 64 KB
    float* diag     = (float*)(ws + (32ull << 20) + (128ull << 10));   // 32 KB
    float* srp      = (float*)(ws + (32ull << 20) + (160ull << 10));   // 512 KB
    float* scp      = (float*)(ws + (32ull << 20) + (672ull << 10));   // 2 MB

    hipMemsetAsync(packed, 0, (64ull << 10), stream);

    conv_bf16<<<(QN * DIMK) / 2048, 256, 0, stream>>>(queue, qb);

    dim3 gp(BROWS / 16, 2);
    proj_fused<<<gp, 256, 0, stream>>>(f1, f2, W1, b1, W2, b2, pcat);

    nn_lse<0, 16><<<256, 512, 0, stream>>>(pcat, qb, packed, nullptr, nullptr, nullptr);

    gather_bf<<<256, 256, 0, stream>>>(packed, qb, nncat);

    nn_lse<1, 2><<<256, 512, 0, stream>>>(nncat, pcat, nullptr, srp, scp, diag);

    reduce_sums<<<32, 256, 0, stream>>>(srp, scp, sums);

    final_loss<<<1, 256, 0, stream>>>(diag, diag + BROWS,
                                      sums, sums + BROWS, sums + 2 * BROWS, sums + 3 * BROWS,
                                      out);
}

// Round 16
// 227.684 us; speedup vs baseline: 1.2372x; 1.2372x over previous
//
#include <hip/hip_runtime.h>

typedef unsigned short ushort_t;
typedef unsigned long long u64_t;
typedef __attribute__((ext_vector_type(8))) short v8bf;
typedef __attribute__((ext_vector_type(8))) unsigned short v8us;
typedef __attribute__((ext_vector_type(8))) unsigned char v8uc;
typedef __attribute__((ext_vector_type(4))) float v4f;

#define BROWS 4096
#define DIMK 256
#define QN 32768
#define EXPSCALE 14.426950408889634f   // 10 * log2(e)

__device__ __forceinline__ ushort_t f2bf(float f) {
    unsigned u = __float_as_uint(f);
    return (ushort_t)((u + 0x7FFFu + ((u >> 16) & 1u)) >> 16);   // RNE
}
// f32 -> OCP e4m3fn, RNE, subnormal-correct for |x|<=1 (our data)
__device__ __forceinline__ unsigned char f2e4m3(float f) {
    unsigned u = __float_as_uint(f);
    unsigned s = (u >> 24) & 0x80u;
    int exp = (int)((u >> 23) & 0xFFu) - 127;
    unsigned man = u & 0x7FFFFFu;
    if (exp >= -6) {
        unsigned m = man >> 20;
        unsigned rest = man & 0xFFFFFu;
        if (rest > 0x80000u || (rest == 0x80000u && (m & 1u))) m++;
        if (m == 8u) { m = 0u; exp++; }
        if (exp > 8) return (unsigned char)(s | 0x7Eu);   // clamp 448
        return (unsigned char)(s | ((unsigned)(exp + 7) << 3) | m);
    }
    if (exp < -10) return (unsigned char)s;
    unsigned full = man | 0x800000u;
    int shift = 20 + (-6 - exp);                  // 21..24
    unsigned m = full >> shift;
    unsigned rest = full & ((1u << shift) - 1u);
    unsigned half = 1u << (shift - 1);
    if (rest > half || (rest == half && (m & 1u))) m++;
    if (m == 8u) return (unsigned char)(s | (1u << 3));
    return (unsigned char)(s | m);
}
__device__ __forceinline__ u64_t shfl_xor_u64(u64_t v, int off) {
    unsigned lo = (unsigned)(v & 0xFFFFFFFFull);
    unsigned hi = (unsigned)(v >> 32);
    lo = (unsigned)__shfl_xor((int)lo, off, 64);
    hi = (unsigned)__shfl_xor((int)hi, off, 64);
    return ((u64_t)hi << 32) | (u64_t)lo;
}
#define GLOAD(g, l_) __builtin_amdgcn_global_load_lds(                         \
    (const __attribute__((address_space(1))) void*)(g),                        \
    (__attribute__((address_space(3))) void*)(l_), 16, 0, 0)

// ---- queue conversion: f32 -> bf16 (for gather/MODE1) + fp8 (for lookup) ----
__global__ __launch_bounds__(256) void conv_q(const float* __restrict__ in,
                                              ushort_t* __restrict__ outb,
                                              unsigned char* __restrict__ out8) {
    const size_t i = ((size_t)blockIdx.x * 256 + threadIdx.x) * 8;
    float4 x = *(const float4*)&in[i];
    float4 y = *(const float4*)&in[i + 4];
    v8us o;
    o[0] = f2bf(x.x); o[1] = f2bf(x.y); o[2] = f2bf(x.z); o[3] = f2bf(x.w);
    o[4] = f2bf(y.x); o[5] = f2bf(y.y); o[6] = f2bf(y.z); o[7] = f2bf(y.w);
    *(v8us*)&outb[i] = o;
    v8uc q;
    q[0] = f2e4m3(x.x); q[1] = f2e4m3(x.y); q[2] = f2e4m3(x.z); q[3] = f2e4m3(x.w);
    q[4] = f2e4m3(y.x); q[5] = f2e4m3(y.y); q[6] = f2e4m3(y.z); q[7] = f2e4m3(y.w);
    *(v8uc*)&out8[i] = q;
}

// ---- fused two-layer projection + L2 norm -> bf16 + fp8 ----
__global__ __launch_bounds__(256) void proj_fused(const float* __restrict__ F1,
                                                  const float* __restrict__ F2,
                                                  const float* __restrict__ W1,
                                                  const float* __restrict__ b1,
                                                  const float* __restrict__ W2,
                                                  const float* __restrict__ b2,
                                                  ushort_t* __restrict__ P,
                                                  unsigned char* __restrict__ P8) {
    __shared__ float fr[16][256];
    __shared__ float hr[16][256];
    __shared__ float partial[4][16];
    const float* F = blockIdx.y ? F2 : F1;
    ushort_t* Po = P + (size_t)blockIdx.y * BROWS * DIMK;
    unsigned char* P8o = P8 + (size_t)blockIdx.y * BROWS * DIMK;
    const int r0 = blockIdx.x << 4, j = threadIdx.x;
    const int w = j >> 6, l = j & 63;
#pragma unroll
    for (int r = 0; r < 16; ++r) fr[r][j] = F[(size_t)(r0 + r) * DIMK + j];
    __syncthreads();
    float acc[16];
    {
        const float bj = b1[j];
#pragma unroll
        for (int r = 0; r < 16; ++r) acc[r] = bj;
        for (int k = 0; k < DIMK; k += 4) {
            const float w0 = W1[(k + 0) * DIMK + j];
            const float w1 = W1[(k + 1) * DIMK + j];
            const float w2 = W1[(k + 2) * DIMK + j];
            const float w3 = W1[(k + 3) * DIMK + j];
#pragma unroll
            for (int r = 0; r < 16; ++r) {
                float4 f = *(const float4*)&fr[r][k];
                acc[r] = fmaf(f.x, w0, acc[r]);
                acc[r] = fmaf(f.y, w1, acc[r]);
                acc[r] = fmaf(f.z, w2, acc[r]);
                acc[r] = fmaf(f.w, w3, acc[r]);
            }
        }
#pragma unroll
        for (int r = 0; r < 16; ++r) hr[r][j] = acc[r] > 0.f ? acc[r] : 0.f;
    }
    __syncthreads();
    {
        const float bj = b2[j];
#pragma unroll
        for (int r = 0; r < 16; ++r) acc[r] = bj;
        for (int k = 0; k < DIMK; k += 4) {
            const float w0 = W2[(k + 0) * DIMK + j];
            const float w1 = W2[(k + 1) * DIMK + j];
            const float w2 = W2[(k + 2) * DIMK + j];
            const float w3 = W2[(k + 3) * DIMK + j];
#pragma unroll
            for (int r = 0; r < 16; ++r) {
                float4 f = *(const float4*)&hr[r][k];
                acc[r] = fmaf(f.x, w0, acc[r]);
                acc[r] = fmaf(f.y, w1, acc[r]);
                acc[r] = fmaf(f.z, w2, acc[r]);
                acc[r] = fmaf(f.w, w3, acc[r]);
            }
        }
    }
#pragma unroll
    for (int r = 0; r < 16; ++r) {
        float s = acc[r] * acc[r];
        s += __shfl_xor(s, 1);  s += __shfl_xor(s, 2);
        s += __shfl_xor(s, 4);  s += __shfl_xor(s, 8);
        s += __shfl_xor(s, 16); s += __shfl_xor(s, 32);
        if (l == 0) partial[w][r] = s;
    }
    __syncthreads();
#pragma unroll
    for (int r = 0; r < 16; ++r) {
        const float tot = partial[0][r] + partial[1][r] + partial[2][r] + partial[3][r];
        const float inv = 1.f / fmaxf(sqrtf(tot), 1e-12f);
        const float v = acc[r] * inv;
        Po[(size_t)(r0 + r) * DIMK + j] = f2bf(v);
        P8o[(size_t)(r0 + r) * DIMK + j] = f2e4m3(v);
    }
}

// ==================== fp8 lookup GEMM + fused argmax (MODE0) ====================
// 512 blocks (2/CU), 256 thr = 4 waves (2Mx2N), wave tile 64x64, acc[4][4]=64 VGPR.
// A panel 128x256 fp8 = 32KB hoisted once; B tile 128colsx128k fp8 = 16KB,
// DOUBLE-buffered; phase p (=t*2+kh): issue stage(p+1), compute 4 K=32 MFMA
// steps from buf[p&1], ONE __syncthreads. LDS 64KB -> 2 blocks/CU.
// L2 math: stage/CU/phase = 32KB covering K=128 -> 293cy/K64-equiv < MFMA ->
// MFMA-bound (bf16 was 585cy > 310cy: L2-BW-bound at 43%).
// fp8 16x16x32 frags: lane l holds row (l&15), 8 bytes at k-octet (l>>4) (same
// geometry as verified bf16 16x16x32). ds_read_b64; swizzles at 16B granules.
__device__ __forceinline__ void stage_b8(const unsigned char* __restrict__ B, int col0,
                                         int kbyte, unsigned char* dst, int tid, int w) {
#pragma unroll
    for (int j = 0; j < 4; ++j) {
        const int slot = (j << 8) + tid;           // 1024 slots of 16B
        const int row = slot >> 3, m = slot & 7;   // row stride 128B
        const int ms = m ^ (row & 7);
        GLOAD(&B[(size_t)(col0 + row) * DIMK + kbyte + (ms << 4)],
              dst + (((j << 8) + (w << 6)) << 4));
    }
}

__global__ __launch_bounds__(256, 2) void nn_argmax8(const unsigned char* __restrict__ Pf8,
                                                     const unsigned char* __restrict__ Qf8,
                                                     u64_t* __restrict__ packed) {
    __shared__ __align__(16) unsigned char Alds[128 * 256];   // 32 KB
    __shared__ __align__(16) unsigned char Bs[2][128 * 128];  // 2 x 16 KB
    const int tid = threadIdx.x;
    const int w = tid >> 6, l = tid & 63;
    const int wr = w >> 1, wc = w & 1;

    const int bid = blockIdx.x;                 // 512 blocks
    const int xcd = bid & 7, i = bid >> 3;
    const int half = xcd & 1;
    const int pairgrp = xcd >> 1;               // owns 8192 cols
    const int arow0 = (i & 31) << 7;
    const int colbase = (pairgrp << 13) + ((i >> 5) << 12);   // 4096 cols/block
    const unsigned char* A = Pf8 + (size_t)half * BROWS * DIMK;
    const unsigned char* B = Qf8;
    u64_t* pk_out = packed + (size_t)half * BROWS;

    // A panel: 2048 slots of 16B; phys 16B-slot m of row r holds logical m^(r&15)
#pragma unroll
    for (int j = 0; j < 8; ++j) {
        const int slot = (j << 8) + tid;
        const int row = slot >> 4, m = slot & 15;
        const int ms = m ^ (row & 15);
        GLOAD(&A[(size_t)(arow0 + row) * DIMK + (ms << 4)],
              Alds + (((j << 8) + (w << 6)) << 4));
    }
    stage_b8(B, colbase, 0, &Bs[0][0], tid, w);
    __syncthreads();   // A + B0 resident

    unsigned best[4][4];
#pragma unroll
    for (int a = 0; a < 4; ++a)
#pragma unroll
        for (int r = 0; r < 4; ++r) best[a][r] = 0u;

    for (int t = 0; t < 32; ++t) {
        v4f acc[4][4];
#pragma unroll
        for (int a = 0; a < 4; ++a)
#pragma unroll
            for (int b = 0; b < 4; ++b) acc[a][b] = (v4f){2.f, 2.f, 2.f, 2.f};

#pragma unroll
        for (int kh = 0; kh < 2; ++kh) {
            const int p = (t << 1) + kh;
            if (p + 1 < 64) {
                const int tn = (p + 1) >> 1, kn = (p + 1) & 1;
                stage_b8(B, colbase + (tn << 7), kn << 7, &Bs[(p + 1) & 1][0], tid, w);
            }
            const unsigned char* bufr = &Bs[p & 1][0];
#pragma unroll
            for (int c = 0; c < 4; ++c) {
                long av[4], bv[4];
#pragma unroll
                for (int mi = 0; mi < 4; ++mi) {
                    const int row = (wr << 6) + (mi << 4) + (l & 15);
                    const int o = (kh << 4) + (c << 2) + (l >> 4);
                    const int phys = (((o >> 1) ^ (row & 15)) << 4) + ((o & 1) << 3);
                    av[mi] = *(const long*)&Alds[(row << 8) + phys];
                }
#pragma unroll
                for (int nj = 0; nj < 4; ++nj) {
                    const int row = (wc << 6) + (nj << 4) + (l & 15);
                    const int o = (c << 2) + (l >> 4);
                    const int phys = (((o >> 1) ^ (row & 7)) << 4) + ((o & 1) << 3);
                    bv[nj] = *(const long*)&bufr[(row << 7) + phys];
                }
#pragma unroll
                for (int mi = 0; mi < 4; ++mi)
#pragma unroll
                    for (int nj = 0; nj < 4; ++nj)
                        acc[mi][nj] = __builtin_amdgcn_mfma_f32_16x16x32_fp8_fp8(
                            av[mi], bv[nj], acc[mi][nj], 0, 0, 0);
            }
            __syncthreads();   // drains own stage(p+1); buffer released
        }
        // running argmax: (bits(v+2) & 0xFFFFFF80) | (t<<2) | nj, uint-monotone
#pragma unroll
        for (int mi = 0; mi < 4; ++mi)
#pragma unroll
            for (int r = 0; r < 4; ++r) {
                unsigned m = (__float_as_uint(acc[mi][0][r]) & 0xFFFFFF80u) |
                             ((unsigned)t << 2);
#pragma unroll
                for (int nj = 1; nj < 4; ++nj) {
                    unsigned c = (__float_as_uint(acc[mi][nj][r]) & 0xFFFFFF80u) |
                                 ((unsigned)t << 2) | (unsigned)nj;
                    m = c > m ? c : m;
                }
                if (m > best[mi][r]) best[mi][r] = m;
            }
    }

#pragma unroll
    for (int mi = 0; mi < 4; ++mi)
#pragma unroll
        for (int r = 0; r < 4; ++r) {
            const unsigned wb = best[mi][r];
            const unsigned col = (unsigned)(colbase + (int)(((wb >> 2) & 31u) << 7) +
                                            (wc << 6) + (int)((wb & 3u) << 4)) + (l & 15);
            u64_t pk = ((u64_t)wb << 32) | (u64_t)(0xFFFFFFFFu - col);
#pragma unroll
            for (int off = 1; off < 16; off <<= 1) {
                u64_t o = shfl_xor_u64(pk, off);
                if (o > pk) pk = o;
            }
            if ((l & 15) == 0)
                atomicMax(&pk_out[arow0 + (wr << 6) + (mi << 4) + ((l >> 4) << 2) + r], pk);
        }
}

// ==================== bf16 LSE GEMM (R13-proven, MODE1 only) ====================
__device__ __forceinline__ void stage_panel(const ushort_t* __restrict__ M, int grow0,
                                            ushort_t* lds, int w, int l) {
#pragma unroll
    for (int j = 0; j < 16; ++j) {
        const int seg = (j << 2) + w;
        const int row = (seg << 1) + (l >> 5);
        const int s = l & 31;
        const int oct = (s & ~7) | ((s & 7) ^ (row & 7));
        GLOAD(&M[(size_t)(grow0 + row) * DIMK + (oct << 3)], lds + (seg << 9));
    }
}
__device__ __forceinline__ void stage_b32(const ushort_t* __restrict__ B, int col0,
                                          int kelem, ushort_t* dst, int w, int l) {
#pragma unroll
    for (int j = 0; j < 4; ++j) {
        const int seg = (j << 2) + w;
        const int row = (seg << 4) + (l >> 2);
        const int oct = (l & 3) ^ ((l >> 3) & 3);
        GLOAD(&B[(size_t)(col0 + row) * DIMK + kelem + (oct << 3)], dst + (seg << 9));
    }
}

template <int NT>
__global__ __launch_bounds__(256, 2) void lse_gemm(const ushort_t* __restrict__ Abase,
                                                   const ushort_t* __restrict__ Bbase,
                                                   float* __restrict__ srp,
                                                   float* __restrict__ scp,
                                                   float* __restrict__ diag) {
    __shared__ __align__(16) ushort_t Alds[128 * 256];   // 64 KB
    __shared__ __align__(16) ushort_t Bs[256 * 32];      // 16 KB
    const int tid = threadIdx.x;
    const int w = tid >> 6, l = tid & 63;
    const int wr = w >> 1, wc = w & 1;

    const int z = blockIdx.x >> 8;
    const int i = blockIdx.x & 255;
    const int rowblk = i & 31;
    const int colstrip = i >> 5;
    const int arow0 = rowblk << 7;
    const int colbase = colstrip << 9;
    const ushort_t* A = Abase + (size_t)z * BROWS * DIMK;
    const ushort_t* B = Bbase + (size_t)(1 - z) * BROWS * DIMK;
    float* dg = diag + (size_t)z * BROWS;

    stage_panel(A, arow0, (ushort_t*)Alds, w, l);

    float rsum[4][4];
#pragma unroll
    for (int a = 0; a < 4; ++a)
#pragma unroll
        for (int r = 0; r < 4; ++r) rsum[a][r] = 0.f;

    for (int t = 0; t < NT; ++t) {
        v4f acc[4][8];
#pragma unroll
        for (int a = 0; a < 4; ++a)
#pragma unroll
            for (int b = 0; b < 8; ++b) acc[a][b] = (v4f){0.f, 0.f, 0.f, 0.f};

#pragma unroll
        for (int k0 = 0; k0 < 8; ++k0) {
            stage_b32(B, colbase + (t << 8), k0 << 5, (ushort_t*)Bs, w, l);
            __syncthreads();
            const int lo = l >> 4;
            v8bf av[4], bv[8];
#pragma unroll
            for (int mi = 0; mi < 4; ++mi) {
                const int row = (wr << 6) + (mi << 4) + (l & 15);
                const int phys = ((k0 >> 1) << 3) | ((((k0 & 1) << 2) + lo) ^ (row & 7));
                av[mi] = *(const v8bf*)&Alds[(row << 8) + (phys << 3)];
            }
#pragma unroll
            for (int nj = 0; nj < 8; ++nj) {
                const int row = (wc << 7) + (nj << 4) + (l & 15);
                const int phys = lo ^ ((row >> 1) & 3);
                bv[nj] = *(const v8bf*)&Bs[(row << 5) + (phys << 3)];
            }
#pragma unroll
            for (int mi = 0; mi < 4; ++mi)
#pragma unroll
                for (int nj = 0; nj < 8; ++nj)
                    acc[mi][nj] = __builtin_amdgcn_mfma_f32_16x16x32_bf16(
                        av[mi], bv[nj], acc[mi][nj], 0, 0, 0);
            __syncthreads();
        }

        const int cb = colbase + (t << 8);
#pragma unroll
        for (int mi = 0; mi < 4; ++mi)
#pragma unroll
            for (int nj = 0; nj < 8; ++nj) {
                const int gr16 = arow0 + (wr << 6) + (mi << 4);
                const int gc16 = cb + (wc << 7) + (nj << 4);
                if (gr16 == gc16) {
#pragma unroll
                    for (int r = 0; r < 4; ++r) {
                        const int rr = ((l >> 4) << 2) + r;
                        if ((l & 15) == rr) dg[gr16 + rr] = acc[mi][nj][r] * 10.0f;
                    }
                }
            }
#pragma unroll
        for (int mi = 0; mi < 4; ++mi)
#pragma unroll
            for (int nj = 0; nj < 8; ++nj) {
                v4f tv = acc[mi][nj];
                tv[0] = exp2f(tv[0] * EXPSCALE);
                tv[1] = exp2f(tv[1] * EXPSCALE);
                tv[2] = exp2f(tv[2] * EXPSCALE);
                tv[3] = exp2f(tv[3] * EXPSCALE);
                acc[mi][nj] = tv;
            }
#pragma unroll
        for (int mi = 0; mi < 4; ++mi)
#pragma unroll
            for (int r = 0; r < 4; ++r) {
                float s = 0.f;
#pragma unroll
                for (int nj = 0; nj < 8; ++nj) s += acc[mi][nj][r];
                rsum[mi][r] += s;
            }
#pragma unroll
        for (int nj = 0; nj < 8; ++nj) {
            float s = 0.f;
#pragma unroll
            for (int mi = 0; mi < 4; ++mi)
#pragma unroll
                for (int r = 0; r < 4; ++r) s += acc[mi][nj][r];
            s += __shfl_xor(s, 16); s += __shfl_xor(s, 32);
            if (l < 16)
                scp[((size_t)(z << 6) + (rowblk << 1) + wr) * BROWS +
                    cb + (wc << 7) + (nj << 4) + l] = s;
        }
    }

#pragma unroll
    for (int mi = 0; mi < 4; ++mi)
#pragma unroll
        for (int r = 0; r < 4; ++r) {
            float s = rsum[mi][r];
            s += __shfl_xor(s, 1); s += __shfl_xor(s, 2);
            s += __shfl_xor(s, 4); s += __shfl_xor(s, 8);
            if ((l & 15) == 0)
                srp[((size_t)(z << 4) + (colstrip << 1) + wc) * BROWS +
                    arow0 + (wr << 6) + (mi << 4) + ((l >> 4) << 2) + r] = s;
        }
}

// ---- fold partial strips into sums[4][BROWS] ----
__global__ __launch_bounds__(256) void reduce_sums(const float* __restrict__ srp,
                                                   const float* __restrict__ scp,
                                                   float* __restrict__ sums) {
    const int idx = blockIdx.x * 256 + threadIdx.x;   // 8192
    const int z = idx >> 12, row = idx & 4095;
    float a = 0.f, b = 0.f;
#pragma unroll 4
    for (int s = 0; s < 16; ++s) a += srp[((size_t)(z << 4) + s) * BROWS + row];
#pragma unroll 4
    for (int s = 0; s < 64; ++s) b += scp[((size_t)(z << 6) + s) * BROWS + row];
    sums[(size_t)(2 * z) * BROWS + row] = a;
    sums[(size_t)(2 * z + 1) * BROWS + row] = b;
}

// ---- gather nn rows (bf16): 8 rows/block-iter, 16B/lane ----
__global__ __launch_bounds__(256) void gather_bf(const u64_t* __restrict__ packed,
                                                 const ushort_t* __restrict__ qb,
                                                 ushort_t* __restrict__ nn) {
    const int r8 = threadIdx.x >> 5;
    const int c = threadIdx.x & 31;
    for (int base = blockIdx.x * 8; base < 2 * BROWS; base += (int)gridDim.x * 8) {
        const int i = base + r8;
        const unsigned idx = 0xFFFFFFFFu - (unsigned)(packed[i] & 0xFFFFFFFFull);
        *(v8us*)&nn[(size_t)i * DIMK + (c << 3)] =
            *(const v8us*)&qb[(size_t)idx * DIMK + (c << 3)];
    }
}

__global__ __launch_bounds__(256) void final_loss(const float* __restrict__ d1,
                                                  const float* __restrict__ d2,
                                                  const float* __restrict__ sr1,
                                                  const float* __restrict__ sc1,
                                                  const float* __restrict__ sr2,
                                                  const float* __restrict__ sc2,
                                                  float* __restrict__ out) {
    __shared__ float red[256];
    const int t = threadIdx.x;
    float acc = 0.f;
    for (int i = t; i < BROWS; i += 256) {
        acc += 2.f * (d1[i] + d2[i]) - logf(sr1[i]) - logf(sc1[i]) - logf(sr2[i]) - logf(sc2[i]);
    }
    red[t] = acc;
    __syncthreads();
    for (int s = 128; s > 0; s >>= 1) {
        if (t < s) red[t] += red[t + s];
        __syncthreads();
    }
    if (t == 0) out[0] = -red[0] / (4.0f * (float)BROWS);
}

extern "C" void kernel_launch(void* const* d_in, const int* in_sizes, int n_in,
                              void* d_out, int out_size, void* d_ws, size_t ws_size,
                              hipStream_t stream) {
    const float* f1 = (const float*)d_in[0];
    const float* f2 = (const float*)d_in[1];
    const float* W1 = (const float*)d_in[2];
    const float* b1 = (const float*)d_in[3];
    const float* W2 = (const float*)d_in[4];
    const float* b2 = (const float*)d_in[5];
    const float* queue = (const float*)d_in[6];
    float* out = (float*)d_out;

    char* ws = (char*)d_ws;
    ushort_t* pcat  = (ushort_t*)(ws + (8ull << 20));      // 4 MB: p1 | p2 (bf16)
    ushort_t* nncat = (ushort_t*)(ws + (12ull << 20));     // 4 MB: nn1 | nn2 (bf16)
    ushort_t* qb    = (ushort_t*)(ws + (16ull << 20));     // 16 MB (bf16)
    u64_t* packed   = (u64_t*)(ws + (32ull << 20));        // 64 KB (8192 rows)
    float* sums     = (float*)(ws + (32ull << 20) + (64ull << 10));    // 64 KB
    float* diag     = (float*)(ws + (32ull << 20) + (128ull << 10));   // 32 KB
    float* srp      = (float*)(ws + (32ull << 20) + (160ull << 10));   // 512 KB
    float* scp      = (float*)(ws + (32ull << 20) + (672ull << 10));   // 2 MB
    unsigned char* qf8 = (unsigned char*)(ws + (36ull << 20));         // 8 MB
    unsigned char* pf8 = (unsigned char*)(ws + (44ull << 20));         // 2 MB

    hipMemsetAsync(packed, 0, (64ull << 10), stream);

    conv_q<<<(QN * DIMK) / 2048, 256, 0, stream>>>(queue, qb, qf8);

    dim3 gp(BROWS / 16, 2);
    proj_fused<<<gp, 256, 0, stream>>>(f1, f2, W1, b1, W2, b2, pcat, pf8);

    nn_argmax8<<<512, 256, 0, stream>>>(pf8, qf8, packed);

    gather_bf<<<256, 256, 0, stream>>>(packed, qb, nncat);

    lse_gemm<2><<<512, 256, 0, stream>>>(nncat, pcat, srp, scp, diag);

    reduce_sums<<<32, 256, 0, stream>>>(srp, scp, sums);

    final_loss<<<1, 256, 0, stream>>>(diag, diag + BROWS,
                                      sums, sums + BROWS, sums + 2 * BROWS, sums + 3 * BROWS,
                                      out);
}

// Round 17
// 223.649 us; speedup vs baseline: 1.2595x; 1.0180x over previous
//
#include <hip/hip_runtime.h>

typedef unsigned short ushort_t;
typedef unsigned long long u64_t;
typedef __attribute__((ext_vector_type(8))) short v8bf;
typedef __attribute__((ext_vector_type(8))) unsigned short v8us;
typedef __attribute__((ext_vector_type(8))) unsigned char v8uc;
typedef __attribute__((ext_vector_type(4))) float v4f;

#define BROWS 4096
#define DIMK 256
#define QN 32768
#define EXPSCALE 14.426950408889634f   // 10 * log2(e)

__device__ __forceinline__ ushort_t f2bf(float f) {
    unsigned u = __float_as_uint(f);
    return (ushort_t)((u + 0x7FFFu + ((u >> 16) & 1u)) >> 16);   // RNE
}
// f32 -> OCP e4m3fn, RNE, subnormal-correct for |x|<=1 (our data)
__device__ __forceinline__ unsigned char f2e4m3(float f) {
    unsigned u = __float_as_uint(f);
    unsigned s = (u >> 24) & 0x80u;
    int exp = (int)((u >> 23) & 0xFFu) - 127;
    unsigned man = u & 0x7FFFFFu;
    if (exp >= -6) {
        unsigned m = man >> 20;
        unsigned rest = man & 0xFFFFFu;
        if (rest > 0x80000u || (rest == 0x80000u && (m & 1u))) m++;
        if (m == 8u) { m = 0u; exp++; }
        if (exp > 8) return (unsigned char)(s | 0x7Eu);   // clamp 448
        return (unsigned char)(s | ((unsigned)(exp + 7) << 3) | m);
    }
    if (exp < -10) return (unsigned char)s;
    unsigned full = man | 0x800000u;
    int shift = 20 + (-6 - exp);                  // 21..24
    unsigned m = full >> shift;
    unsigned rest = full & ((1u << shift) - 1u);
    unsigned half = 1u << (shift - 1);
    if (rest > half || (rest == half && (m & 1u))) m++;
    if (m == 8u) return (unsigned char)(s | (1u << 3));
    return (unsigned char)(s | m);
}
__device__ __forceinline__ u64_t shfl_xor_u64(u64_t v, int off) {
    unsigned lo = (unsigned)(v & 0xFFFFFFFFull);
    unsigned hi = (unsigned)(v >> 32);
    lo = (unsigned)__shfl_xor((int)lo, off, 64);
    hi = (unsigned)__shfl_xor((int)hi, off, 64);
    return ((u64_t)hi << 32) | (u64_t)lo;
}
#define GLOAD(g, l_) __builtin_amdgcn_global_load_lds(                         \
    (const __attribute__((address_space(1))) void*)(g),                        \
    (__attribute__((address_space(3))) void*)(l_), 16, 0, 0)

// ---- queue conversion: f32 -> bf16 + fp8.
// fp8 stored HALF-SWAPPED: byte of logical column c lands at c ^ ((row>>3&1)<<3)
// so that LDS frag reads can split rows r/r+8 across 8B halves (bank-spread).
__global__ __launch_bounds__(256) void conv_q(const float* __restrict__ in,
                                              ushort_t* __restrict__ outb,
                                              unsigned char* __restrict__ out8) {
    const size_t i = ((size_t)blockIdx.x * 256 + threadIdx.x) * 8;
    float4 x = *(const float4*)&in[i];
    float4 y = *(const float4*)&in[i + 4];
    v8us o;
    o[0] = f2bf(x.x); o[1] = f2bf(x.y); o[2] = f2bf(x.z); o[3] = f2bf(x.w);
    o[4] = f2bf(y.x); o[5] = f2bf(y.y); o[6] = f2bf(y.z); o[7] = f2bf(y.w);
    *(v8us*)&outb[i] = o;
    v8uc q;
    q[0] = f2e4m3(x.x); q[1] = f2e4m3(x.y); q[2] = f2e4m3(x.z); q[3] = f2e4m3(x.w);
    q[4] = f2e4m3(y.x); q[5] = f2e4m3(y.y); q[6] = f2e4m3(y.z); q[7] = f2e4m3(y.w);
    const int row = (int)(i >> 8);
    const int col = (int)(i & 255);
    *(v8uc*)&out8[((size_t)row << 8) + (col ^ ((((unsigned)row >> 3) & 1u) << 3))] = q;
}

// ---- fused two-layer projection + L2 norm -> bf16 + fp8 (half-swapped) ----
__global__ __launch_bounds__(256) void proj_fused(const float* __restrict__ F1,
                                                  const float* __restrict__ F2,
                                                  const float* __restrict__ W1,
                                                  const float* __restrict__ b1,
                                                  const float* __restrict__ W2,
                                                  const float* __restrict__ b2,
                                                  ushort_t* __restrict__ P,
                                                  unsigned char* __restrict__ P8) {
    __shared__ float fr[16][256];
    __shared__ float hr[16][256];
    __shared__ float partial[4][16];
    const float* F = blockIdx.y ? F2 : F1;
    ushort_t* Po = P + (size_t)blockIdx.y * BROWS * DIMK;
    unsigned char* P8o = P8 + (size_t)blockIdx.y * BROWS * DIMK;
    const int r0 = blockIdx.x << 4, j = threadIdx.x;
    const int w = j >> 6, l = j & 63;
#pragma unroll
    for (int r = 0; r < 16; ++r) fr[r][j] = F[(size_t)(r0 + r) * DIMK + j];
    __syncthreads();
    float acc[16];
    {
        const float bj = b1[j];
#pragma unroll
        for (int r = 0; r < 16; ++r) acc[r] = bj;
        for (int k = 0; k < DIMK; k += 4) {
            const float w0 = W1[(k + 0) * DIMK + j];
            const float w1 = W1[(k + 1) * DIMK + j];
            const float w2 = W1[(k + 2) * DIMK + j];
            const float w3 = W1[(k + 3) * DIMK + j];
#pragma unroll
            for (int r = 0; r < 16; ++r) {
                float4 f = *(const float4*)&fr[r][k];
                acc[r] = fmaf(f.x, w0, acc[r]);
                acc[r] = fmaf(f.y, w1, acc[r]);
                acc[r] = fmaf(f.z, w2, acc[r]);
                acc[r] = fmaf(f.w, w3, acc[r]);
            }
        }
#pragma unroll
        for (int r = 0; r < 16; ++r) hr[r][j] = acc[r] > 0.f ? acc[r] : 0.f;
    }
    __syncthreads();
    {
        const float bj = b2[j];
#pragma unroll
        for (int r = 0; r < 16; ++r) acc[r] = bj;
        for (int k = 0; k < DIMK; k += 4) {
            const float w0 = W2[(k + 0) * DIMK + j];
            const float w1 = W2[(k + 1) * DIMK + j];
            const float w2 = W2[(k + 2) * DIMK + j];
            const float w3 = W2[(k + 3) * DIMK + j];
#pragma unroll
            for (int r = 0; r < 16; ++r) {
                float4 f = *(const float4*)&hr[r][k];
                acc[r] = fmaf(f.x, w0, acc[r]);
                acc[r] = fmaf(f.y, w1, acc[r]);
                acc[r] = fmaf(f.z, w2, acc[r]);
                acc[r] = fmaf(f.w, w3, acc[r]);
            }
        }
    }
#pragma unroll
    for (int r = 0; r < 16; ++r) {
        float s = acc[r] * acc[r];
        s += __shfl_xor(s, 1);  s += __shfl_xor(s, 2);
        s += __shfl_xor(s, 4);  s += __shfl_xor(s, 8);
        s += __shfl_xor(s, 16); s += __shfl_xor(s, 32);
        if (l == 0) partial[w][r] = s;
    }
    __syncthreads();
#pragma unroll
    for (int r = 0; r < 16; ++r) {
        const float tot = partial[0][r] + partial[1][r] + partial[2][r] + partial[3][r];
        const float inv = 1.f / fmaxf(sqrtf(tot), 1e-12f);
        const float v = acc[r] * inv;
        Po[(size_t)(r0 + r) * DIMK + j] = f2bf(v);
        const int prow = r0 + r;
        P8o[((size_t)prow << 8) + (j ^ ((((unsigned)prow >> 3) & 1u) << 3))] = f2e4m3(v);
    }
}

// ==================== fp8 lookup GEMM + fused argmax ====================
// As R16 (512 blocks, 2/CU, A panel 32KB hoisted, B 2x16KB dbuf, 1 barrier/phase)
// + bank-conflict-free frag reads: 16B-slot XOR swizzle (staged) combined with
// 8B half-select h = (o&1) ^ ((row>>3)&1) (pre-swapped in GLOBAL storage since
// global_load_lds can't permute). Rows r/r+8 now hit disjoint bank sets.
__device__ __forceinline__ void stage_b8(const unsigned char* __restrict__ B, int col0,
                                         int kbyte, unsigned char* dst, int tid, int w) {
#pragma unroll
    for (int j = 0; j < 4; ++j) {
        const int slot = (j << 8) + tid;           // 1024 slots of 16B
        const int row = slot >> 3, m = slot & 7;   // row stride 128B
        const int ms = m ^ (row & 7);
        GLOAD(&B[(size_t)(col0 + row) * DIMK + kbyte + (ms << 4)],
              dst + (((j << 8) + (w << 6)) << 4));
    }
}

__global__ __launch_bounds__(256, 2) void nn_argmax8(const unsigned char* __restrict__ Pf8,
                                                     const unsigned char* __restrict__ Qf8,
                                                     u64_t* __restrict__ packed) {
    __shared__ __align__(16) unsigned char Alds[128 * 256];   // 32 KB
    __shared__ __align__(16) unsigned char Bs[2][128 * 128];  // 2 x 16 KB
    const int tid = threadIdx.x;
    const int w = tid >> 6, l = tid & 63;
    const int wr = w >> 1, wc = w & 1;

    const int bid = blockIdx.x;                 // 512 blocks
    const int xcd = bid & 7, i = bid >> 3;
    const int half = xcd & 1;
    const int pairgrp = xcd >> 1;               // owns 8192 cols
    const int arow0 = (i & 31) << 7;
    const int colbase = (pairgrp << 13) + ((i >> 5) << 12);   // 4096 cols/block
    const unsigned char* A = Pf8 + (size_t)half * BROWS * DIMK;
    const unsigned char* B = Qf8;
    u64_t* pk_out = packed + (size_t)half * BROWS;

    // A panel: 2048 slots of 16B; phys 16B-slot m of row r holds logical m^(r&15)
#pragma unroll
    for (int j = 0; j < 8; ++j) {
        const int slot = (j << 8) + tid;
        const int row = slot >> 4, m = slot & 15;
        const int ms = m ^ (row & 15);
        GLOAD(&A[(size_t)(arow0 + row) * DIMK + (ms << 4)],
              Alds + (((j << 8) + (w << 6)) << 4));
    }
    stage_b8(B, colbase, 0, &Bs[0][0], tid, w);
    __syncthreads();   // A + B0 resident

    unsigned best[4][4];
#pragma unroll
    for (int a = 0; a < 4; ++a)
#pragma unroll
        for (int r = 0; r < 4; ++r) best[a][r] = 0u;

    for (int t = 0; t < 32; ++t) {
        v4f acc[4][4];
#pragma unroll
        for (int a = 0; a < 4; ++a)
#pragma unroll
            for (int b = 0; b < 4; ++b) acc[a][b] = (v4f){2.f, 2.f, 2.f, 2.f};

#pragma unroll
        for (int kh = 0; kh < 2; ++kh) {
            const int p = (t << 1) + kh;
            if (p + 1 < 64) {
                const int tn = (p + 1) >> 1, kn = (p + 1) & 1;
                stage_b8(B, colbase + (tn << 7), kn << 7, &Bs[(p + 1) & 1][0], tid, w);
            }
            const unsigned char* bufr = &Bs[p & 1][0];
#pragma unroll
            for (int c = 0; c < 4; ++c) {
                long av[4], bv[4];
#pragma unroll
                for (int mi = 0; mi < 4; ++mi) {
                    const int row = (wr << 6) + (mi << 4) + (l & 15);
                    const int o = (kh << 4) + (c << 2) + (l >> 4);
                    const int phys = (((o >> 1) ^ (row & 15)) << 4) +
                                     (((o ^ (row >> 3)) & 1) << 3);
                    av[mi] = *(const long*)&Alds[(row << 8) + phys];
                }
#pragma unroll
                for (int nj = 0; nj < 4; ++nj) {
                    const int row = (wc << 6) + (nj << 4) + (l & 15);
                    const int o = (c << 2) + (l >> 4);
                    const int phys = (((o >> 1) ^ (row & 7)) << 4) +
                                     (((o ^ (row >> 3)) & 1) << 3);
                    bv[nj] = *(const long*)&bufr[(row << 7) + phys];
                }
#pragma unroll
                for (int mi = 0; mi < 4; ++mi)
#pragma unroll
                    for (int nj = 0; nj < 4; ++nj)
                        acc[mi][nj] = __builtin_amdgcn_mfma_f32_16x16x32_fp8_fp8(
                            av[mi], bv[nj], acc[mi][nj], 0, 0, 0);
            }
            __syncthreads();   // drains own stage(p+1); buffer released
        }
        // running argmax: (bits(v+2) & 0xFFFFFF80) | (t<<2) | nj, uint-monotone
#pragma unroll
        for (int mi = 0; mi < 4; ++mi)
#pragma unroll
            for (int r = 0; r < 4; ++r) {
                unsigned m = (__float_as_uint(acc[mi][0][r]) & 0xFFFFFF80u) |
                             ((unsigned)t << 2);
#pragma unroll
                for (int nj = 1; nj < 4; ++nj) {
                    unsigned c = (__float_as_uint(acc[mi][nj][r]) & 0xFFFFFF80u) |
                                 ((unsigned)t << 2) | (unsigned)nj;
                    m = c > m ? c : m;
                }
                if (m > best[mi][r]) best[mi][r] = m;
            }
    }

#pragma unroll
    for (int mi = 0; mi < 4; ++mi)
#pragma unroll
        for (int r = 0; r < 4; ++r) {
            const unsigned wb = best[mi][r];
            const unsigned col = (unsigned)(colbase + (int)(((wb >> 2) & 31u) << 7) +
                                            (wc << 6) + (int)((wb & 3u) << 4)) + (l & 15);
            u64_t pk = ((u64_t)wb << 32) | (u64_t)(0xFFFFFFFFu - col);
#pragma unroll
            for (int off = 1; off < 16; off <<= 1) {
                u64_t o = shfl_xor_u64(pk, off);
                if (o > pk) pk = o;
            }
            if ((l & 15) == 0)
                atomicMax(&pk_out[arow0 + (wr << 6) + (mi << 4) + ((l >> 4) << 2) + r], pk);
        }
}

// ==================== bf16 LSE GEMM (R13-proven) ====================
__device__ __forceinline__ void stage_panel(const ushort_t* __restrict__ M, int grow0,
                                            ushort_t* lds, int w, int l) {
#pragma unroll
    for (int j = 0; j < 16; ++j) {
        const int seg = (j << 2) + w;
        const int row = (seg << 1) + (l >> 5);
        const int s = l & 31;
        const int oct = (s & ~7) | ((s & 7) ^ (row & 7));
        GLOAD(&M[(size_t)(grow0 + row) * DIMK + (oct << 3)], lds + (seg << 9));
    }
}
__device__ __forceinline__ void stage_b32(const ushort_t* __restrict__ B, int col0,
                                          int kelem, ushort_t* dst, int w, int l) {
#pragma unroll
    for (int j = 0; j < 4; ++j) {
        const int seg = (j << 2) + w;
        const int row = (seg << 4) + (l >> 2);
        const int oct = (l & 3) ^ ((l >> 3) & 3);
        GLOAD(&B[(size_t)(col0 + row) * DIMK + kelem + (oct << 3)], dst + (seg << 9));
    }
}

template <int NT>
__global__ __launch_bounds__(256, 2) void lse_gemm(const ushort_t* __restrict__ Abase,
                                                   const ushort_t* __restrict__ Bbase,
                                                   float* __restrict__ srp,
                                                   float* __restrict__ scp,
                                                   float* __restrict__ diag) {
    __shared__ __align__(16) ushort_t Alds[128 * 256];   // 64 KB
    __shared__ __align__(16) ushort_t Bs[256 * 32];      // 16 KB
    const int tid = threadIdx.x;
    const int w = tid >> 6, l = tid & 63;
    const int wr = w >> 1, wc = w & 1;

    const int z = blockIdx.x >> 8;
    const int i = blockIdx.x & 255;
    const int rowblk = i & 31;
    const int colstrip = i >> 5;
    const int arow0 = rowblk << 7;
    const int colbase = colstrip << 9;
    const ushort_t* A = Abase + (size_t)z * BROWS * DIMK;
    const ushort_t* B = Bbase + (size_t)(1 - z) * BROWS * DIMK;
    float* dg = diag + (size_t)z * BROWS;

    stage_panel(A, arow0, (ushort_t*)Alds, w, l);

    float rsum[4][4];
#pragma unroll
    for (int a = 0; a < 4; ++a)
#pragma unroll
        for (int r = 0; r < 4; ++r) rsum[a][r] = 0.f;

    for (int t = 0; t < NT; ++t) {
        v4f acc[4][8];
#pragma unroll
        for (int a = 0; a < 4; ++a)
#pragma unroll
            for (int b = 0; b < 8; ++b) acc[a][b] = (v4f){0.f, 0.f, 0.f, 0.f};

#pragma unroll
        for (int k0 = 0; k0 < 8; ++k0) {
            stage_b32(B, colbase + (t << 8), k0 << 5, (ushort_t*)Bs, w, l);
            __syncthreads();
            const int lo = l >> 4;
            v8bf av[4], bv[8];
#pragma unroll
            for (int mi = 0; mi < 4; ++mi) {
                const int row = (wr << 6) + (mi << 4) + (l & 15);
                const int phys = ((k0 >> 1) << 3) | ((((k0 & 1) << 2) + lo) ^ (row & 7));
                av[mi] = *(const v8bf*)&Alds[(row << 8) + (phys << 3)];
            }
#pragma unroll
            for (int nj = 0; nj < 8; ++nj) {
                const int row = (wc << 7) + (nj << 4) + (l & 15);
                const int phys = lo ^ ((row >> 1) & 3);
                bv[nj] = *(const v8bf*)&Bs[(row << 5) + (phys << 3)];
            }
#pragma unroll
            for (int mi = 0; mi < 4; ++mi)
#pragma unroll
                for (int nj = 0; nj < 8; ++nj)
                    acc[mi][nj] = __builtin_amdgcn_mfma_f32_16x16x32_bf16(
                        av[mi], bv[nj], acc[mi][nj], 0, 0, 0);
            __syncthreads();
        }

        const int cb = colbase + (t << 8);
#pragma unroll
        for (int mi = 0; mi < 4; ++mi)
#pragma unroll
            for (int nj = 0; nj < 8; ++nj) {
                const int gr16 = arow0 + (wr << 6) + (mi << 4);
                const int gc16 = cb + (wc << 7) + (nj << 4);
                if (gr16 == gc16) {
#pragma unroll
                    for (int r = 0; r < 4; ++r) {
                        const int rr = ((l >> 4) << 2) + r;
                        if ((l & 15) == rr) dg[gr16 + rr] = acc[mi][nj][r] * 10.0f;
                    }
                }
            }
#pragma unroll
        for (int mi = 0; mi < 4; ++mi)
#pragma unroll
            for (int nj = 0; nj < 8; ++nj) {
                v4f tv = acc[mi][nj];
                tv[0] = exp2f(tv[0] * EXPSCALE);
                tv[1] = exp2f(tv[1] * EXPSCALE);
                tv[2] = exp2f(tv[2] * EXPSCALE);
                tv[3] = exp2f(tv[3] * EXPSCALE);
                acc[mi][nj] = tv;
            }
#pragma unroll
        for (int mi = 0; mi < 4; ++mi)
#pragma unroll
            for (int r = 0; r < 4; ++r) {
                float s = 0.f;
#pragma unroll
                for (int nj = 0; nj < 8; ++nj) s += acc[mi][nj][r];
                rsum[mi][r] += s;
            }
#pragma unroll
        for (int nj = 0; nj < 8; ++nj) {
            float s = 0.f;
#pragma unroll
            for (int mi = 0; mi < 4; ++mi)
#pragma unroll
                for (int r = 0; r < 4; ++r) s += acc[mi][nj][r];
            s += __shfl_xor(s, 16); s += __shfl_xor(s, 32);
            if (l < 16)
                scp[((size_t)(z << 6) + (rowblk << 1) + wr) * BROWS +
                    cb + (wc << 7) + (nj << 4) + l] = s;
        }
    }

#pragma unroll
    for (int mi = 0; mi < 4; ++mi)
#pragma unroll
        for (int r = 0; r < 4; ++r) {
            float s = rsum[mi][r];
            s += __shfl_xor(s, 1); s += __shfl_xor(s, 2);
            s += __shfl_xor(s, 4); s += __shfl_xor(s, 8);
            if ((l & 15) == 0)
                srp[((size_t)(z << 4) + (colstrip << 1) + wc) * BROWS +
                    arow0 + (wr << 6) + (mi << 4) + ((l >> 4) << 2) + r] = s;
        }
}

// ---- fold partial strips into sums[4][BROWS] ----
__global__ __launch_bounds__(256) void reduce_sums(const float* __restrict__ srp,
                                                   const float* __restrict__ scp,
                                                   float* __restrict__ sums) {
    const int idx = blockIdx.x * 256 + threadIdx.x;   // 8192
    const int z = idx >> 12, row = idx & 4095;
    float a = 0.f, b = 0.f;
#pragma unroll 4
    for (int s = 0; s < 16; ++s) a += srp[((size_t)(z << 4) + s) * BROWS + row];
#pragma unroll 4
    for (int s = 0; s < 64; ++s) b += scp[((size_t)(z << 6) + s) * BROWS + row];
    sums[(size_t)(2 * z) * BROWS + row] = a;
    sums[(size_t)(2 * z + 1) * BROWS + row] = b;
}

// ---- gather nn rows (bf16): 8 rows/block-iter, 16B/lane ----
__global__ __launch_bounds__(256) void gather_bf(const u64_t* __restrict__ packed,
                                                 const ushort_t* __restrict__ qb,
                                                 ushort_t* __restrict__ nn) {
    const int r8 = threadIdx.x >> 5;
    const int c = threadIdx.x & 31;
    for (int base = blockIdx.x * 8; base < 2 * BROWS; base += (int)gridDim.x * 8) {
        const int i = base + r8;
        const unsigned idx = 0xFFFFFFFFu - (unsigned)(packed[i] & 0xFFFFFFFFull);
        *(v8us*)&nn[(size_t)i * DIMK + (c << 3)] =
            *(const v8us*)&qb[(size_t)idx * DIMK + (c << 3)];
    }
}

__global__ __launch_bounds__(256) void final_loss(const float* __restrict__ d1,
                                                  const float* __restrict__ d2,
                                                  const float* __restrict__ sr1,
                                                  const float* __restrict__ sc1,
                                                  const float* __restrict__ sr2,
                                                  const float* __restrict__ sc2,
                                                  float* __restrict__ out) {
    __shared__ float red[256];
    const int t = threadIdx.x;
    float acc = 0.f;
    for (int i = t; i < BROWS; i += 256) {
        acc += 2.f * (d1[i] + d2[i]) - logf(sr1[i]) - logf(sc1[i]) - logf(sr2[i]) - logf(sc2[i]);
    }
    red[t] = acc;
    __syncthreads();
    for (int s = 128; s > 0; s >>= 1) {
        if (t < s) red[t] += red[t + s];
        __syncthreads();
    }
    if (t == 0) out[0] = -red[0] / (4.0f * (float)BROWS);
}

extern "C" void kernel_launch(void* const* d_in, const int* in_sizes, int n_in,
                              void* d_out, int out_size, void* d_ws, size_t ws_size,
                              hipStream_t stream) {
    const float* f1 = (const float*)d_in[0];
    const float* f2 = (const float*)d_in[1];
    const float* W1 = (const float*)d_in[2];
    const float* b1 = (const float*)d_in[3];
    const float* W2 = (const float*)d_in[4];
    const float* b2 = (const float*)d_in[5];
    const float* queue = (const float*)d_in[6];
    float* out = (float*)d_out;

    char* ws = (char*)d_ws;
    ushort_t* pcat  = (ushort_t*)(ws + (8ull << 20));      // 4 MB: p1 | p2 (bf16)
    ushort_t* nncat = (ushort_t*)(ws + (12ull << 20));     // 4 MB: nn1 | nn2 (bf16)
    ushort_t* qb    = (ushort_t*)(ws + (16ull << 20));     // 16 MB (bf16)
    u64_t* packed   = (u64_t*)(ws + (32ull << 20));        // 64 KB (8192 rows)
    float* sums     = (float*)(ws + (32ull << 20) + (64ull << 10));    // 64 KB
    float* diag     = (float*)(ws + (32ull << 20) + (128ull << 10));   // 32 KB
    float* srp      = (float*)(ws + (32ull << 20) + (160ull << 10));   // 512 KB
    float* scp      = (float*)(ws + (32ull << 20) + (672ull << 10));   // 2 MB
    unsigned char* qf8 = (unsigned char*)(ws + (36ull << 20));         // 8 MB
    unsigned char* pf8 = (unsigned char*)(ws + (44ull << 20));         // 2 MB

    hipMemsetAsync(packed, 0, (64ull << 10), stream);

    conv_q<<<(QN * DIMK) / 2048, 256, 0, stream>>>(queue, qb, qf8);

    dim3 gp(BROWS / 16, 2);
    proj_fused<<<gp, 256, 0, stream>>>(f1, f2, W1, b1, W2, b2, pcat, pf8);

    nn_argmax8<<<512, 256, 0, stream>>>(pf8, qf8, packed);

    gather_bf<<<256, 256, 0, stream>>>(packed, qb, nncat);

    lse_gemm<2><<<512, 256, 0, stream>>>(nncat, pcat, srp, scp, diag);

    reduce_sums<<<32, 256, 0, stream>>>(srp, scp, sums);

    final_loss<<<1, 256, 0, stream>>>(diag, diag + BROWS,
                                      sums, sums + BROWS, sums + 2 * BROWS, sums + 3 * BROWS,
                                      out);
}

// Round 18
// 212.548 us; speedup vs baseline: 1.3253x; 1.0522x over previous
//
#include <hip/hip_runtime.h>

typedef unsigned short ushort_t;
typedef unsigned long long u64_t;
typedef __attribute__((ext_vector_type(8))) unsigned char v8uc;
typedef __attribute__((ext_vector_type(4))) float v4f;

#define BROWS 4096
#define DIMK 256
#define QN 32768
#define EXPSCALE 14.426950408889634f   // 10 * log2(e)

// f32 -> OCP e4m3fn, RNE, subnormal-correct for |x|<=1 (our data)
__device__ __forceinline__ unsigned char f2e4m3(float f) {
    unsigned u = __float_as_uint(f);
    unsigned s = (u >> 24) & 0x80u;
    int exp = (int)((u >> 23) & 0xFFu) - 127;
    unsigned man = u & 0x7FFFFFu;
    if (exp >= -6) {
        unsigned m = man >> 20;
        unsigned rest = man & 0xFFFFFu;
        if (rest > 0x80000u || (rest == 0x80000u && (m & 1u))) m++;
        if (m == 8u) { m = 0u; exp++; }
        if (exp > 8) return (unsigned char)(s | 0x7Eu);   // clamp 448
        return (unsigned char)(s | ((unsigned)(exp + 7) << 3) | m);
    }
    if (exp < -10) return (unsigned char)s;
    unsigned full = man | 0x800000u;
    int shift = 20 + (-6 - exp);                  // 21..24
    unsigned m = full >> shift;
    unsigned rest = full & ((1u << shift) - 1u);
    unsigned half = 1u << (shift - 1);
    if (rest > half || (rest == half && (m & 1u))) m++;
    if (m == 8u) return (unsigned char)(s | (1u << 3));
    return (unsigned char)(s | m);
}
__device__ __forceinline__ u64_t shfl_xor_u64(u64_t v, int off) {
    unsigned lo = (unsigned)(v & 0xFFFFFFFFull);
    unsigned hi = (unsigned)(v >> 32);
    lo = (unsigned)__shfl_xor((int)lo, off, 64);
    hi = (unsigned)__shfl_xor((int)hi, off, 64);
    return ((u64_t)hi << 32) | (u64_t)lo;
}
#define GLOAD(g, l_) __builtin_amdgcn_global_load_lds(                         \
    (const __attribute__((address_space(1))) void*)(g),                        \
    (__attribute__((address_space(3))) void*)(l_), 16, 0, 0)

// ---- queue conversion: f32 -> fp8 only, HALF-SWAPPED (byte of logical col c
// stored at c ^ ((row>>3&1)<<3)) so fp8 LDS frag reads are bank-spread. ----
__global__ __launch_bounds__(256) void conv_q8(const float* __restrict__ in,
                                               unsigned char* __restrict__ out8) {
    const size_t i = ((size_t)blockIdx.x * 256 + threadIdx.x) * 8;
    float4 x = *(const float4*)&in[i];
    float4 y = *(const float4*)&in[i + 4];
    v8uc q;
    q[0] = f2e4m3(x.x); q[1] = f2e4m3(x.y); q[2] = f2e4m3(x.z); q[3] = f2e4m3(x.w);
    q[4] = f2e4m3(y.x); q[5] = f2e4m3(y.y); q[6] = f2e4m3(y.z); q[7] = f2e4m3(y.w);
    const int row = (int)(i >> 8);
    const int col = (int)(i & 255);
    *(v8uc*)&out8[((size_t)row << 8) + (col ^ ((((unsigned)row >> 3) & 1u) << 3))] = q;
}

// ---- fused two-layer projection + L2 norm -> fp8 (half-swapped) ----
__global__ __launch_bounds__(256) void proj_fused(const float* __restrict__ F1,
                                                  const float* __restrict__ F2,
                                                  const float* __restrict__ W1,
                                                  const float* __restrict__ b1,
                                                  const float* __restrict__ W2,
                                                  const float* __restrict__ b2,
                                                  unsigned char* __restrict__ P8) {
    __shared__ float fr[16][256];
    __shared__ float hr[16][256];
    __shared__ float partial[4][16];
    const float* F = blockIdx.y ? F2 : F1;
    unsigned char* P8o = P8 + (size_t)blockIdx.y * BROWS * DIMK;
    const int r0 = blockIdx.x << 4, j = threadIdx.x;
    const int w = j >> 6, l = j & 63;
#pragma unroll
    for (int r = 0; r < 16; ++r) fr[r][j] = F[(size_t)(r0 + r) * DIMK + j];
    __syncthreads();
    float acc[16];
    {
        const float bj = b1[j];
#pragma unroll
        for (int r = 0; r < 16; ++r) acc[r] = bj;
        for (int k = 0; k < DIMK; k += 4) {
            const float w0 = W1[(k + 0) * DIMK + j];
            const float w1 = W1[(k + 1) * DIMK + j];
            const float w2 = W1[(k + 2) * DIMK + j];
            const float w3 = W1[(k + 3) * DIMK + j];
#pragma unroll
            for (int r = 0; r < 16; ++r) {
                float4 f = *(const float4*)&fr[r][k];
                acc[r] = fmaf(f.x, w0, acc[r]);
                acc[r] = fmaf(f.y, w1, acc[r]);
                acc[r] = fmaf(f.z, w2, acc[r]);
                acc[r] = fmaf(f.w, w3, acc[r]);
            }
        }
#pragma unroll
        for (int r = 0; r < 16; ++r) hr[r][j] = acc[r] > 0.f ? acc[r] : 0.f;
    }
    __syncthreads();
    {
        const float bj = b2[j];
#pragma unroll
        for (int r = 0; r < 16; ++r) acc[r] = bj;
        for (int k = 0; k < DIMK; k += 4) {
            const float w0 = W2[(k + 0) * DIMK + j];
            const float w1 = W2[(k + 1) * DIMK + j];
            const float w2 = W2[(k + 2) * DIMK + j];
            const float w3 = W2[(k + 3) * DIMK + j];
#pragma unroll
            for (int r = 0; r < 16; ++r) {
                float4 f = *(const float4*)&hr[r][k];
                acc[r] = fmaf(f.x, w0, acc[r]);
                acc[r] = fmaf(f.y, w1, acc[r]);
                acc[r] = fmaf(f.z, w2, acc[r]);
                acc[r] = fmaf(f.w, w3, acc[r]);
            }
        }
    }
#pragma unroll
    for (int r = 0; r < 16; ++r) {
        float s = acc[r] * acc[r];
        s += __shfl_xor(s, 1);  s += __shfl_xor(s, 2);
        s += __shfl_xor(s, 4);  s += __shfl_xor(s, 8);
        s += __shfl_xor(s, 16); s += __shfl_xor(s, 32);
        if (l == 0) partial[w][r] = s;
    }
    __syncthreads();
#pragma unroll
    for (int r = 0; r < 16; ++r) {
        const float tot = partial[0][r] + partial[1][r] + partial[2][r] + partial[3][r];
        const float inv = 1.f / fmaxf(sqrtf(tot), 1e-12f);
        const int prow = r0 + r;
        P8o[((size_t)prow << 8) + (j ^ ((((unsigned)prow >> 3) & 1u) << 3))] =
            f2e4m3(acc[r] * inv);
    }
}

// ==================== shared fp8 GEMM shell (R17-proven) ====================
// B tile: 128 cols x 256 K-bytes per t, staged as 2 half-tiles of 16KB (kbyte
// 0/128); 16B-slot swizzle m^(row&7); frag reads add 8B half-select
// (o ^ (row>>3)) & 1 using the globally pre-swapped layout. Conflict-free.
__device__ __forceinline__ void stage_b8(const unsigned char* __restrict__ B, int col0,
                                         int kbyte, unsigned char* dst, int tid, int w) {
#pragma unroll
    for (int j = 0; j < 4; ++j) {
        const int slot = (j << 8) + tid;           // 1024 slots of 16B
        const int row = slot >> 3, m = slot & 7;   // row stride 128B
        const int ms = m ^ (row & 7);
        GLOAD(&B[(size_t)(col0 + row) * DIMK + kbyte + (ms << 4)],
              dst + (((j << 8) + (w << 6)) << 4));
    }
}
__device__ __forceinline__ void stage_a8(const unsigned char* __restrict__ A, int arow0,
                                         unsigned char* Alds, int tid, int w) {
#pragma unroll
    for (int j = 0; j < 8; ++j) {
        const int slot = (j << 8) + tid;           // 2048 slots of 16B
        const int row = slot >> 4, m = slot & 15;  // row stride 256B
        const int ms = m ^ (row & 15);
        GLOAD(&A[(size_t)(arow0 + row) * DIMK + (ms << 4)],
              Alds + (((j << 8) + (w << 6)) << 4));
    }
}

// ---- fp8 lookup GEMM + fused argmax (512 blocks, 2/CU) ----
__global__ __launch_bounds__(256, 2) void nn_argmax8(const unsigned char* __restrict__ Pf8,
                                                     const unsigned char* __restrict__ Qf8,
                                                     u64_t* __restrict__ packed) {
    __shared__ __align__(16) unsigned char Alds[128 * 256];   // 32 KB
    __shared__ __align__(16) unsigned char Bs[2][128 * 128];  // 2 x 16 KB
    const int tid = threadIdx.x;
    const int w = tid >> 6, l = tid & 63;
    const int wr = w >> 1, wc = w & 1;

    const int bid = blockIdx.x;                 // 512 blocks
    const int xcd = bid & 7, i = bid >> 3;
    const int half = xcd & 1;
    const int pairgrp = xcd >> 1;               // owns 8192 cols
    const int arow0 = (i & 31) << 7;
    const int colbase = (pairgrp << 13) + ((i >> 5) << 12);   // 4096 cols/block
    const unsigned char* A = Pf8 + (size_t)half * BROWS * DIMK;
    const unsigned char* B = Qf8;
    u64_t* pk_out = packed + (size_t)half * BROWS;

    stage_a8(A, arow0, Alds, tid, w);
    stage_b8(B, colbase, 0, &Bs[0][0], tid, w);
    __syncthreads();

    unsigned best[4][4];
#pragma unroll
    for (int a = 0; a < 4; ++a)
#pragma unroll
        for (int r = 0; r < 4; ++r) best[a][r] = 0u;

    for (int t = 0; t < 32; ++t) {
        v4f acc[4][4];
#pragma unroll
        for (int a = 0; a < 4; ++a)
#pragma unroll
            for (int b = 0; b < 4; ++b) acc[a][b] = (v4f){2.f, 2.f, 2.f, 2.f};

#pragma unroll
        for (int kh = 0; kh < 2; ++kh) {
            const int p = (t << 1) + kh;
            if (p + 1 < 64) {
                const int tn = (p + 1) >> 1, kn = (p + 1) & 1;
                stage_b8(B, colbase + (tn << 7), kn << 7, &Bs[(p + 1) & 1][0], tid, w);
            }
            const unsigned char* bufr = &Bs[p & 1][0];
#pragma unroll
            for (int c = 0; c < 4; ++c) {
                long av[4], bv[4];
#pragma unroll
                for (int mi = 0; mi < 4; ++mi) {
                    const int row = (wr << 6) + (mi << 4) + (l & 15);
                    const int o = (kh << 4) + (c << 2) + (l >> 4);
                    const int phys = (((o >> 1) ^ (row & 15)) << 4) +
                                     (((o ^ (row >> 3)) & 1) << 3);
                    av[mi] = *(const long*)&Alds[(row << 8) + phys];
                }
#pragma unroll
                for (int nj = 0; nj < 4; ++nj) {
                    const int row = (wc << 6) + (nj << 4) + (l & 15);
                    const int o = (c << 2) + (l >> 4);
                    const int phys = (((o >> 1) ^ (row & 7)) << 4) +
                                     (((o ^ (row >> 3)) & 1) << 3);
                    bv[nj] = *(const long*)&bufr[(row << 7) + phys];
                }
#pragma unroll
                for (int mi = 0; mi < 4; ++mi)
#pragma unroll
                    for (int nj = 0; nj < 4; ++nj)
                        acc[mi][nj] = __builtin_amdgcn_mfma_f32_16x16x32_fp8_fp8(
                            av[mi], bv[nj], acc[mi][nj], 0, 0, 0);
            }
            __syncthreads();
        }
#pragma unroll
        for (int mi = 0; mi < 4; ++mi)
#pragma unroll
            for (int r = 0; r < 4; ++r) {
                unsigned m = (__float_as_uint(acc[mi][0][r]) & 0xFFFFFF80u) |
                             ((unsigned)t << 2);
#pragma unroll
                for (int nj = 1; nj < 4; ++nj) {
                    unsigned c = (__float_as_uint(acc[mi][nj][r]) & 0xFFFFFF80u) |
                                 ((unsigned)t << 2) | (unsigned)nj;
                    m = c > m ? c : m;
                }
                if (m > best[mi][r]) best[mi][r] = m;
            }
    }

#pragma unroll
    for (int mi = 0; mi < 4; ++mi)
#pragma unroll
        for (int r = 0; r < 4; ++r) {
            const unsigned wb = best[mi][r];
            const unsigned col = (unsigned)(colbase + (int)(((wb >> 2) & 31u) << 7) +
                                            (wc << 6) + (int)((wb & 3u) << 4)) + (l & 15);
            u64_t pk = ((u64_t)wb << 32) | (u64_t)(0xFFFFFFFFu - col);
#pragma unroll
            for (int off = 1; off < 16; off <<= 1) {
                u64_t o = shfl_xor_u64(pk, off);
                if (o > pk) pk = o;
            }
            if ((l & 15) == 0)
                atomicMax(&pk_out[arow0 + (wr << 6) + (mi << 4) + ((l >> 4) << 2) + r], pk);
        }
}

// ---- gather nn rows in fp8, fixing the 8B half-swap parity (src row idx vs
// dest row i may differ in bit 3) ----
__global__ __launch_bounds__(256) void gather8(const u64_t* __restrict__ packed,
                                               const unsigned char* __restrict__ qf8,
                                               unsigned char* __restrict__ nn8) {
    const int r8 = threadIdx.x >> 5;   // 8 rows per block-iter
    const int c = threadIdx.x & 31;    // 32 chunks of 8 bytes
    for (int base = blockIdx.x * 8; base < 2 * BROWS; base += (int)gridDim.x * 8) {
        const int i = base + r8;
        const unsigned idx = 0xFFFFFFFFu - (unsigned)(packed[i] & 0xFFFFFFFFull);
        const unsigned sp = (idx >> 3) & 1u;
        const unsigned dp = (((unsigned)i) >> 3) & 1u;
        *(u64_t*)&nn8[((size_t)i << 8) + ((unsigned)(c << 3) ^ (dp << 3))] =
            *(const u64_t*)&qf8[((size_t)idx << 8) + ((unsigned)(c << 3) ^ (sp << 3))];
    }
}

// ---- fp8 LSE GEMM: same shell, epilogue = diag + exp-sums (partial strips) ----
// 512 blocks: z(2) x rowblk(32) x colstrip(8 of 512 cols), NT=4 tiles of 128.
__global__ __launch_bounds__(256, 2) void lse_gemm8(const unsigned char* __restrict__ nn8,
                                                    const unsigned char* __restrict__ pf8,
                                                    float* __restrict__ srp,
                                                    float* __restrict__ scp,
                                                    float* __restrict__ diag) {
    __shared__ __align__(16) unsigned char Alds[128 * 256];   // 32 KB
    __shared__ __align__(16) unsigned char Bs[2][128 * 128];  // 2 x 16 KB
    const int tid = threadIdx.x;
    const int w = tid >> 6, l = tid & 63;
    const int wr = w >> 1, wc = w & 1;

    const int z = blockIdx.x >> 8;
    const int i = blockIdx.x & 255;
    const int rowblk = i & 31;
    const int colstrip = i >> 5;               // 8 strips of 512 cols
    const int arow0 = rowblk << 7;
    const int colbase = colstrip << 9;
    const unsigned char* A = nn8 + (size_t)z * BROWS * DIMK;
    const unsigned char* B = pf8 + (size_t)(1 - z) * BROWS * DIMK;
    float* dg = diag + (size_t)z * BROWS;

    stage_a8(A, arow0, Alds, tid, w);
    stage_b8(B, colbase, 0, &Bs[0][0], tid, w);
    __syncthreads();

    float rsum[4][4];
#pragma unroll
    for (int a = 0; a < 4; ++a)
#pragma unroll
        for (int r = 0; r < 4; ++r) rsum[a][r] = 0.f;

    for (int t = 0; t < 4; ++t) {
        v4f acc[4][4];
#pragma unroll
        for (int a = 0; a < 4; ++a)
#pragma unroll
            for (int b = 0; b < 4; ++b) acc[a][b] = (v4f){0.f, 0.f, 0.f, 0.f};

#pragma unroll
        for (int kh = 0; kh < 2; ++kh) {
            const int p = (t << 1) + kh;
            if (p + 1 < 8) {
                const int tn = (p + 1) >> 1, kn = (p + 1) & 1;
                stage_b8(B, colbase + (tn << 7), kn << 7, &Bs[(p + 1) & 1][0], tid, w);
            }
            const unsigned char* bufr = &Bs[p & 1][0];
#pragma unroll
            for (int c = 0; c < 4; ++c) {
                long av[4], bv[4];
#pragma unroll
                for (int mi = 0; mi < 4; ++mi) {
                    const int row = (wr << 6) + (mi << 4) + (l & 15);
                    const int o = (kh << 4) + (c << 2) + (l >> 4);
                    const int phys = (((o >> 1) ^ (row & 15)) << 4) +
                                     (((o ^ (row >> 3)) & 1) << 3);
                    av[mi] = *(const long*)&Alds[(row << 8) + phys];
                }
#pragma unroll
                for (int nj = 0; nj < 4; ++nj) {
                    const int row = (wc << 6) + (nj << 4) + (l & 15);
                    const int o = (c << 2) + (l >> 4);
                    const int phys = (((o >> 1) ^ (row & 7)) << 4) +
                                     (((o ^ (row >> 3)) & 1) << 3);
                    bv[nj] = *(const long*)&bufr[(row << 7) + phys];
                }
#pragma unroll
                for (int mi = 0; mi < 4; ++mi)
#pragma unroll
                    for (int nj = 0; nj < 4; ++nj)
                        acc[mi][nj] = __builtin_amdgcn_mfma_f32_16x16x32_fp8_fp8(
                            av[mi], bv[nj], acc[mi][nj], 0, 0, 0);
            }
            __syncthreads();
        }

        const int cb = colbase + (t << 7);
        // diag from raw scores (before exp); unique writer per cell
#pragma unroll
        for (int mi = 0; mi < 4; ++mi)
#pragma unroll
            for (int nj = 0; nj < 4; ++nj) {
                const int gr16 = arow0 + (wr << 6) + (mi << 4);
                const int gc16 = cb + (wc << 6) + (nj << 4);
                if (gr16 == gc16) {
#pragma unroll
                    for (int r = 0; r < 4; ++r) {
                        const int rr = ((l >> 4) << 2) + r;
                        if ((l & 15) == rr) dg[gr16 + rr] = acc[mi][nj][r] * 10.0f;
                    }
                }
            }
#pragma unroll
        for (int mi = 0; mi < 4; ++mi)
#pragma unroll
            for (int nj = 0; nj < 4; ++nj) {
                v4f tv = acc[mi][nj];
                tv[0] = exp2f(tv[0] * EXPSCALE);
                tv[1] = exp2f(tv[1] * EXPSCALE);
                tv[2] = exp2f(tv[2] * EXPSCALE);
                tv[3] = exp2f(tv[3] * EXPSCALE);
                acc[mi][nj] = tv;
            }
#pragma unroll
        for (int mi = 0; mi < 4; ++mi)
#pragma unroll
            for (int r = 0; r < 4; ++r) {
                float s = 0.f;
#pragma unroll
                for (int nj = 0; nj < 4; ++nj) s += acc[mi][nj][r];
                rsum[mi][r] += s;
            }
        // col partials: unique strip (z,rowblk,wr); plain stores
#pragma unroll
        for (int nj = 0; nj < 4; ++nj) {
            float s = 0.f;
#pragma unroll
            for (int mi = 0; mi < 4; ++mi)
#pragma unroll
                for (int r = 0; r < 4; ++r) s += acc[mi][nj][r];
            s += __shfl_xor(s, 16); s += __shfl_xor(s, 32);
            if (l < 16)
                scp[((size_t)(z << 6) + (rowblk << 1) + wr) * BROWS +
                    cb + (wc << 6) + (nj << 4) + l] = s;
        }
    }

    // row partials: unique strip (z, colstrip, wc)
#pragma unroll
    for (int mi = 0; mi < 4; ++mi)
#pragma unroll
        for (int r = 0; r < 4; ++r) {
            float s = rsum[mi][r];
            s += __shfl_xor(s, 1); s += __shfl_xor(s, 2);
            s += __shfl_xor(s, 4); s += __shfl_xor(s, 8);
            if ((l & 15) == 0)
                srp[((size_t)(z << 4) + (colstrip << 1) + wc) * BROWS +
                    arow0 + (wr << 6) + (mi << 4) + ((l >> 4) << 2) + r] = s;
        }
}

// ---- fold partial strips into sums[4][BROWS] ----
__global__ __launch_bounds__(256) void reduce_sums(const float* __restrict__ srp,
                                                   const float* __restrict__ scp,
                                                   float* __restrict__ sums) {
    const int idx = blockIdx.x * 256 + threadIdx.x;   // 8192
    const int z = idx >> 12, row = idx & 4095;
    float a = 0.f, b = 0.f;
#pragma unroll 4
    for (int s = 0; s < 16; ++s) a += srp[((size_t)(z << 4) + s) * BROWS + row];
#pragma unroll 4
    for (int s = 0; s < 64; ++s) b += scp[((size_t)(z << 6) + s) * BROWS + row];
    sums[(size_t)(2 * z) * BROWS + row] = a;
    sums[(size_t)(2 * z + 1) * BROWS + row] = b;
}

__global__ __launch_bounds__(256) void final_loss(const float* __restrict__ d1,
                                                  const float* __restrict__ d2,
                                                  const float* __restrict__ sr1,
                                                  const float* __restrict__ sc1,
                                                  const float* __restrict__ sr2,
                                                  const float* __restrict__ sc2,
                                                  float* __restrict__ out) {
    __shared__ float red[256];
    const int t = threadIdx.x;
    float acc = 0.f;
    for (int i = t; i < BROWS; i += 256) {
        acc += 2.f * (d1[i] + d2[i]) - logf(sr1[i]) - logf(sc1[i]) - logf(sr2[i]) - logf(sc2[i]);
    }
    red[t] = acc;
    __syncthreads();
    for (int s = 128; s > 0; s >>= 1) {
        if (t < s) red[t] += red[t + s];
        __syncthreads();
    }
    if (t == 0) out[0] = -red[0] / (4.0f * (float)BROWS);
}

extern "C" void kernel_launch(void* const* d_in, const int* in_sizes, int n_in,
                              void* d_out, int out_size, void* d_ws, size_t ws_size,
                              hipStream_t stream) {
    const float* f1 = (const float*)d_in[0];
    const float* f2 = (const float*)d_in[1];
    const float* W1 = (const float*)d_in[2];
    const float* b1 = (const float*)d_in[3];
    const float* W2 = (const float*)d_in[4];
    const float* b2 = (const float*)d_in[5];
    const float* queue = (const float*)d_in[6];
    float* out = (float*)d_out;

    char* ws = (char*)d_ws;
    unsigned char* qf8 = (unsigned char*)ws;                    // 8 MB
    unsigned char* pf8 = (unsigned char*)(ws + (8ull << 20));   // 2 MB
    unsigned char* nn8 = (unsigned char*)(ws + (10ull << 20));  // 2 MB
    u64_t* packed = (u64_t*)(ws + (12ull << 20));               // 64 KB
    float* sums   = (float*)(ws + (12ull << 20) + (64ull << 10));   // 64 KB
    float* diag   = (float*)(ws + (12ull << 20) + (128ull << 10));  // 32 KB
    float* srp    = (float*)(ws + (12ull << 20) + (160ull << 10));  // 512 KB
    float* scp    = (float*)(ws + (12ull << 20) + (672ull << 10));  // 2 MB

    hipMemsetAsync(packed, 0, (64ull << 10), stream);

    conv_q8<<<(QN * DIMK) / 2048, 256, 0, stream>>>(queue, qf8);

    dim3 gp(BROWS / 16, 2);
    proj_fused<<<gp, 256, 0, stream>>>(f1, f2, W1, b1, W2, b2, pf8);

    nn_argmax8<<<512, 256, 0, stream>>>(pf8, qf8, packed);

    gather8<<<256, 256, 0, stream>>>(packed, qf8, nn8);

    lse_gemm8<<<512, 256, 0, stream>>>(nn8, pf8, srp, scp, diag);

    reduce_sums<<<32, 256, 0, stream>>>(srp, scp, sums);

    final_loss<<<1, 256, 0, stream>>>(diag, diag + BROWS,
                                      sums, sums + BROWS, sums + 2 * BROWS, sums + 3 * BROWS,
                                      out);
}

// Round 19
// 212.341 us; speedup vs baseline: 1.3266x; 1.0010x over previous
//
#include <hip/hip_runtime.h>

typedef unsigned short ushort_t;
typedef unsigned long long u64_t;
typedef __attribute__((ext_vector_type(8))) unsigned char v8uc;
typedef __attribute__((ext_vector_type(4))) float v4f;

#define BROWS 4096
#define DIMK 256
#define QN 32768
#define EXPSCALE 14.426950408889634f   // 10 * log2(e)

// f32 -> OCP e4m3fn, RNE, subnormal-correct for |x|<=1 (our data)
__device__ __forceinline__ unsigned char f2e4m3(float f) {
    unsigned u = __float_as_uint(f);
    unsigned s = (u >> 24) & 0x80u;
    int exp = (int)((u >> 23) & 0xFFu) - 127;
    unsigned man = u & 0x7FFFFFu;
    if (exp >= -6) {
        unsigned m = man >> 20;
        unsigned rest = man & 0xFFFFFu;
        if (rest > 0x80000u || (rest == 0x80000u && (m & 1u))) m++;
        if (m == 8u) { m = 0u; exp++; }
        if (exp > 8) return (unsigned char)(s | 0x7Eu);   // clamp 448
        return (unsigned char)(s | ((unsigned)(exp + 7) << 3) | m);
    }
    if (exp < -10) return (unsigned char)s;
    unsigned full = man | 0x800000u;
    int shift = 20 + (-6 - exp);                  // 21..24
    unsigned m = full >> shift;
    unsigned rest = full & ((1u << shift) - 1u);
    unsigned half = 1u << (shift - 1);
    if (rest > half || (rest == half && (m & 1u))) m++;
    if (m == 8u) return (unsigned char)(s | (1u << 3));
    return (unsigned char)(s | m);
}
__device__ __forceinline__ u64_t shfl_xor_u64(u64_t v, int off) {
    unsigned lo = (unsigned)(v & 0xFFFFFFFFull);
    unsigned hi = (unsigned)(v >> 32);
    lo = (unsigned)__shfl_xor((int)lo, off, 64);
    hi = (unsigned)__shfl_xor((int)hi, off, 64);
    return ((u64_t)hi << 32) | (u64_t)lo;
}
#define GLOAD(g, l_) __builtin_amdgcn_global_load_lds(                         \
    (const __attribute__((address_space(1))) void*)(g),                        \
    (__attribute__((address_space(3))) void*)(l_), 16, 0, 0)

// ==================== prep: conv(queue->fp8) + zero(packed) + proj ====================
// blocks [0,4096): queue f32 -> fp8 (half-swapped layout); first 32 also zero packed.
// blocks [4096,4608): fused 2-layer projection + L2 norm -> fp8 (half-swapped).
__global__ __launch_bounds__(256) void prep(const float* __restrict__ queue,
                                            const float* __restrict__ F1,
                                            const float* __restrict__ F2,
                                            const float* __restrict__ W1,
                                            const float* __restrict__ b1,
                                            const float* __restrict__ W2,
                                            const float* __restrict__ b2,
                                            unsigned char* __restrict__ qf8,
                                            unsigned char* __restrict__ pf8,
                                            u64_t* __restrict__ packed) {
    __shared__ float fr[16][256];
    __shared__ float hr[16][256];
    __shared__ float partial[4][16];
    const int bid = blockIdx.x;
    const int j = threadIdx.x;

    if (bid < 4096) {
        // ---- conv path ----
        if (bid < 32) packed[(bid << 8) + j] = 0ull;
        const size_t i = ((size_t)bid * 256 + j) * 8;
        float4 x = *(const float4*)&queue[i];
        float4 y = *(const float4*)&queue[i + 4];
        v8uc q;
        q[0] = f2e4m3(x.x); q[1] = f2e4m3(x.y); q[2] = f2e4m3(x.z); q[3] = f2e4m3(x.w);
        q[4] = f2e4m3(y.x); q[5] = f2e4m3(y.y); q[6] = f2e4m3(y.z); q[7] = f2e4m3(y.w);
        const int row = (int)(i >> 8);
        const int col = (int)(i & 255);
        *(v8uc*)&qf8[((size_t)row << 8) + (col ^ ((((unsigned)row >> 3) & 1u) << 3))] = q;
        return;
    }

    // ---- proj path ----
    const int pb = bid - 4096;                 // 0..511
    const int half = pb >> 8;                  // f1 / f2
    const int r0 = (pb & 255) << 4;
    const float* F = half ? F2 : F1;
    unsigned char* P8o = pf8 + (size_t)half * BROWS * DIMK;
    const int w = j >> 6, l = j & 63;
#pragma unroll
    for (int r = 0; r < 16; ++r) fr[r][j] = F[(size_t)(r0 + r) * DIMK + j];
    __syncthreads();
    float acc[16];
    {
        const float bj = b1[j];
#pragma unroll
        for (int r = 0; r < 16; ++r) acc[r] = bj;
        for (int k = 0; k < DIMK; k += 4) {
            const float w0 = W1[(k + 0) * DIMK + j];
            const float w1 = W1[(k + 1) * DIMK + j];
            const float w2 = W1[(k + 2) * DIMK + j];
            const float w3 = W1[(k + 3) * DIMK + j];
#pragma unroll
            for (int r = 0; r < 16; ++r) {
                float4 f = *(const float4*)&fr[r][k];
                acc[r] = fmaf(f.x, w0, acc[r]);
                acc[r] = fmaf(f.y, w1, acc[r]);
                acc[r] = fmaf(f.z, w2, acc[r]);
                acc[r] = fmaf(f.w, w3, acc[r]);
            }
        }
#pragma unroll
        for (int r = 0; r < 16; ++r) hr[r][j] = acc[r] > 0.f ? acc[r] : 0.f;
    }
    __syncthreads();
    {
        const float bj = b2[j];
#pragma unroll
        for (int r = 0; r < 16; ++r) acc[r] = bj;
        for (int k = 0; k < DIMK; k += 4) {
            const float w0 = W2[(k + 0) * DIMK + j];
            const float w1 = W2[(k + 1) * DIMK + j];
            const float w2 = W2[(k + 2) * DIMK + j];
            const float w3 = W2[(k + 3) * DIMK + j];
#pragma unroll
            for (int r = 0; r < 16; ++r) {
                float4 f = *(const float4*)&hr[r][k];
                acc[r] = fmaf(f.x, w0, acc[r]);
                acc[r] = fmaf(f.y, w1, acc[r]);
                acc[r] = fmaf(f.z, w2, acc[r]);
                acc[r] = fmaf(f.w, w3, acc[r]);
            }
        }
    }
#pragma unroll
    for (int r = 0; r < 16; ++r) {
        float s = acc[r] * acc[r];
        s += __shfl_xor(s, 1);  s += __shfl_xor(s, 2);
        s += __shfl_xor(s, 4);  s += __shfl_xor(s, 8);
        s += __shfl_xor(s, 16); s += __shfl_xor(s, 32);
        if (l == 0) partial[w][r] = s;
    }
    __syncthreads();
#pragma unroll
    for (int r = 0; r < 16; ++r) {
        const float tot = partial[0][r] + partial[1][r] + partial[2][r] + partial[3][r];
        const float inv = 1.f / fmaxf(sqrtf(tot), 1e-12f);
        const int prow = r0 + r;
        P8o[((size_t)prow << 8) + (j ^ ((((unsigned)prow >> 3) & 1u) << 3))] =
            f2e4m3(acc[r] * inv);
    }
}

// ==================== shared fp8 GEMM shell (R17-proven) ====================
__device__ __forceinline__ void stage_b8(const unsigned char* __restrict__ B, int col0,
                                         int kbyte, unsigned char* dst, int tid, int w) {
#pragma unroll
    for (int j = 0; j < 4; ++j) {
        const int slot = (j << 8) + tid;           // 1024 slots of 16B
        const int row = slot >> 3, m = slot & 7;   // row stride 128B
        const int ms = m ^ (row & 7);
        GLOAD(&B[(size_t)(col0 + row) * DIMK + kbyte + (ms << 4)],
              dst + (((j << 8) + (w << 6)) << 4));
    }
}
__device__ __forceinline__ void stage_a8(const unsigned char* __restrict__ A, int arow0,
                                         unsigned char* Alds, int tid, int w) {
#pragma unroll
    for (int j = 0; j < 8; ++j) {
        const int slot = (j << 8) + tid;           // 2048 slots of 16B
        const int row = slot >> 4, m = slot & 15;  // row stride 256B
        const int ms = m ^ (row & 15);
        GLOAD(&A[(size_t)(arow0 + row) * DIMK + (ms << 4)],
              Alds + (((j << 8) + (w << 6)) << 4));
    }
}

// ---- fp8 lookup GEMM + fused argmax (512 blocks, 2/CU) ----
__global__ __launch_bounds__(256, 2) void nn_argmax8(const unsigned char* __restrict__ Pf8,
                                                     const unsigned char* __restrict__ Qf8,
                                                     u64_t* __restrict__ packed) {
    __shared__ __align__(16) unsigned char Alds[128 * 256];   // 32 KB
    __shared__ __align__(16) unsigned char Bs[2][128 * 128];  // 2 x 16 KB
    const int tid = threadIdx.x;
    const int w = tid >> 6, l = tid & 63;
    const int wr = w >> 1, wc = w & 1;

    const int bid = blockIdx.x;                 // 512 blocks
    const int xcd = bid & 7, i = bid >> 3;
    const int half = xcd & 1;
    const int pairgrp = xcd >> 1;               // owns 8192 cols
    const int arow0 = (i & 31) << 7;
    const int colbase = (pairgrp << 13) + ((i >> 5) << 12);   // 4096 cols/block
    const unsigned char* A = Pf8 + (size_t)half * BROWS * DIMK;
    const unsigned char* B = Qf8;
    u64_t* pk_out = packed + (size_t)half * BROWS;

    stage_a8(A, arow0, Alds, tid, w);
    stage_b8(B, colbase, 0, &Bs[0][0], tid, w);
    __syncthreads();

    unsigned best[4][4];
#pragma unroll
    for (int a = 0; a < 4; ++a)
#pragma unroll
        for (int r = 0; r < 4; ++r) best[a][r] = 0u;

    for (int t = 0; t < 32; ++t) {
        v4f acc[4][4];
#pragma unroll
        for (int a = 0; a < 4; ++a)
#pragma unroll
            for (int b = 0; b < 4; ++b) acc[a][b] = (v4f){2.f, 2.f, 2.f, 2.f};

#pragma unroll
        for (int kh = 0; kh < 2; ++kh) {
            const int p = (t << 1) + kh;
            if (p + 1 < 64) {
                const int tn = (p + 1) >> 1, kn = (p + 1) & 1;
                stage_b8(B, colbase + (tn << 7), kn << 7, &Bs[(p + 1) & 1][0], tid, w);
            }
            const unsigned char* bufr = &Bs[p & 1][0];
#pragma unroll
            for (int c = 0; c < 4; ++c) {
                long av[4], bv[4];
#pragma unroll
                for (int mi = 0; mi < 4; ++mi) {
                    const int row = (wr << 6) + (mi << 4) + (l & 15);
                    const int o = (kh << 4) + (c << 2) + (l >> 4);
                    const int phys = (((o >> 1) ^ (row & 15)) << 4) +
                                     (((o ^ (row >> 3)) & 1) << 3);
                    av[mi] = *(const long*)&Alds[(row << 8) + phys];
                }
#pragma unroll
                for (int nj = 0; nj < 4; ++nj) {
                    const int row = (wc << 6) + (nj << 4) + (l & 15);
                    const int o = (c << 2) + (l >> 4);
                    const int phys = (((o >> 1) ^ (row & 7)) << 4) +
                                     (((o ^ (row >> 3)) & 1) << 3);
                    bv[nj] = *(const long*)&bufr[(row << 7) + phys];
                }
#pragma unroll
                for (int mi = 0; mi < 4; ++mi)
#pragma unroll
                    for (int nj = 0; nj < 4; ++nj)
                        acc[mi][nj] = __builtin_amdgcn_mfma_f32_16x16x32_fp8_fp8(
                            av[mi], bv[nj], acc[mi][nj], 0, 0, 0);
            }
            __syncthreads();
        }
#pragma unroll
        for (int mi = 0; mi < 4; ++mi)
#pragma unroll
            for (int r = 0; r < 4; ++r) {
                unsigned m = (__float_as_uint(acc[mi][0][r]) & 0xFFFFFF80u) |
                             ((unsigned)t << 2);
#pragma unroll
                for (int nj = 1; nj < 4; ++nj) {
                    unsigned c = (__float_as_uint(acc[mi][nj][r]) & 0xFFFFFF80u) |
                                 ((unsigned)t << 2) | (unsigned)nj;
                    m = c > m ? c : m;
                }
                if (m > best[mi][r]) best[mi][r] = m;
            }
    }

#pragma unroll
    for (int mi = 0; mi < 4; ++mi)
#pragma unroll
        for (int r = 0; r < 4; ++r) {
            const unsigned wb = best[mi][r];
            const unsigned col = (unsigned)(colbase + (int)(((wb >> 2) & 31u) << 7) +
                                            (wc << 6) + (int)((wb & 3u) << 4)) + (l & 15);
            u64_t pk = ((u64_t)wb << 32) | (u64_t)(0xFFFFFFFFu - col);
#pragma unroll
            for (int off = 1; off < 16; off <<= 1) {
                u64_t o = shfl_xor_u64(pk, off);
                if (o > pk) pk = o;
            }
            if ((l & 15) == 0)
                atomicMax(&pk_out[arow0 + (wr << 6) + (mi << 4) + ((l >> 4) << 2) + r], pk);
        }
}

// ---- gather nn rows in fp8 (half-swap parity fix) + zero out[0] ----
__global__ __launch_bounds__(256) void gather8(const u64_t* __restrict__ packed,
                                               const unsigned char* __restrict__ qf8,
                                               unsigned char* __restrict__ nn8,
                                               float* __restrict__ out) {
    if (blockIdx.x == 0 && threadIdx.x == 0) out[0] = 0.f;
    const int r8 = threadIdx.x >> 5;   // 8 rows per block-iter
    const int c = threadIdx.x & 31;    // 32 chunks of 8 bytes
    for (int base = blockIdx.x * 8; base < 2 * BROWS; base += (int)gridDim.x * 8) {
        const int i = base + r8;
        const unsigned idx = 0xFFFFFFFFu - (unsigned)(packed[i] & 0xFFFFFFFFull);
        const unsigned sp = (idx >> 3) & 1u;
        const unsigned dp = (((unsigned)i) >> 3) & 1u;
        *(u64_t*)&nn8[((size_t)i << 8) + ((unsigned)(c << 3) ^ (dp << 3))] =
            *(const u64_t*)&qf8[((size_t)idx << 8) + ((unsigned)(c << 3) ^ (sp << 3))];
    }
}

// ---- fp8 LSE GEMM: same shell, epilogue = diag + exp-sums (partial strips) ----
__global__ __launch_bounds__(256, 2) void lse_gemm8(const unsigned char* __restrict__ nn8,
                                                    const unsigned char* __restrict__ pf8,
                                                    float* __restrict__ srp,
                                                    float* __restrict__ scp,
                                                    float* __restrict__ diag) {
    __shared__ __align__(16) unsigned char Alds[128 * 256];   // 32 KB
    __shared__ __align__(16) unsigned char Bs[2][128 * 128];  // 2 x 16 KB
    const int tid = threadIdx.x;
    const int w = tid >> 6, l = tid & 63;
    const int wr = w >> 1, wc = w & 1;

    const int z = blockIdx.x >> 8;
    const int i = blockIdx.x & 255;
    const int rowblk = i & 31;
    const int colstrip = i >> 5;               // 8 strips of 512 cols
    const int arow0 = rowblk << 7;
    const int colbase = colstrip << 9;
    const unsigned char* A = nn8 + (size_t)z * BROWS * DIMK;
    const unsigned char* B = pf8 + (size_t)(1 - z) * BROWS * DIMK;
    float* dg = diag + (size_t)z * BROWS;

    stage_a8(A, arow0, Alds, tid, w);
    stage_b8(B, colbase, 0, &Bs[0][0], tid, w);
    __syncthreads();

    float rsum[4][4];
#pragma unroll
    for (int a = 0; a < 4; ++a)
#pragma unroll
        for (int r = 0; r < 4; ++r) rsum[a][r] = 0.f;

    for (int t = 0; t < 4; ++t) {
        v4f acc[4][4];
#pragma unroll
        for (int a = 0; a < 4; ++a)
#pragma unroll
            for (int b = 0; b < 4; ++b) acc[a][b] = (v4f){0.f, 0.f, 0.f, 0.f};

#pragma unroll
        for (int kh = 0; kh < 2; ++kh) {
            const int p = (t << 1) + kh;
            if (p + 1 < 8) {
                const int tn = (p + 1) >> 1, kn = (p + 1) & 1;
                stage_b8(B, colbase + (tn << 7), kn << 7, &Bs[(p + 1) & 1][0], tid, w);
            }
            const unsigned char* bufr = &Bs[p & 1][0];
#pragma unroll
            for (int c = 0; c < 4; ++c) {
                long av[4], bv[4];
#pragma unroll
                for (int mi = 0; mi < 4; ++mi) {
                    const int row = (wr << 6) + (mi << 4) + (l & 15);
                    const int o = (kh << 4) + (c << 2) + (l >> 4);
                    const int phys = (((o >> 1) ^ (row & 15)) << 4) +
                                     (((o ^ (row >> 3)) & 1) << 3);
                    av[mi] = *(const long*)&Alds[(row << 8) + phys];
                }
#pragma unroll
                for (int nj = 0; nj < 4; ++nj) {
                    const int row = (wc << 6) + (nj << 4) + (l & 15);
                    const int o = (c << 2) + (l >> 4);
                    const int phys = (((o >> 1) ^ (row & 7)) << 4) +
                                     (((o ^ (row >> 3)) & 1) << 3);
                    bv[nj] = *(const long*)&bufr[(row << 7) + phys];
                }
#pragma unroll
                for (int mi = 0; mi < 4; ++mi)
#pragma unroll
                    for (int nj = 0; nj < 4; ++nj)
                        acc[mi][nj] = __builtin_amdgcn_mfma_f32_16x16x32_fp8_fp8(
                            av[mi], bv[nj], acc[mi][nj], 0, 0, 0);
            }
            __syncthreads();
        }

        const int cb = colbase + (t << 7);
#pragma unroll
        for (int mi = 0; mi < 4; ++mi)
#pragma unroll
            for (int nj = 0; nj < 4; ++nj) {
                const int gr16 = arow0 + (wr << 6) + (mi << 4);
                const int gc16 = cb + (wc << 6) + (nj << 4);
                if (gr16 == gc16) {
#pragma unroll
                    for (int r = 0; r < 4; ++r) {
                        const int rr = ((l >> 4) << 2) + r;
                        if ((l & 15) == rr) dg[gr16 + rr] = acc[mi][nj][r] * 10.0f;
                    }
                }
            }
#pragma unroll
        for (int mi = 0; mi < 4; ++mi)
#pragma unroll
            for (int nj = 0; nj < 4; ++nj) {
                v4f tv = acc[mi][nj];
                tv[0] = exp2f(tv[0] * EXPSCALE);
                tv[1] = exp2f(tv[1] * EXPSCALE);
                tv[2] = exp2f(tv[2] * EXPSCALE);
                tv[3] = exp2f(tv[3] * EXPSCALE);
                acc[mi][nj] = tv;
            }
#pragma unroll
        for (int mi = 0; mi < 4; ++mi)
#pragma unroll
            for (int r = 0; r < 4; ++r) {
                float s = 0.f;
#pragma unroll
                for (int nj = 0; nj < 4; ++nj) s += acc[mi][nj][r];
                rsum[mi][r] += s;
            }
#pragma unroll
        for (int nj = 0; nj < 4; ++nj) {
            float s = 0.f;
#pragma unroll
            for (int mi = 0; mi < 4; ++mi)
#pragma unroll
                for (int r = 0; r < 4; ++r) s += acc[mi][nj][r];
            s += __shfl_xor(s, 16); s += __shfl_xor(s, 32);
            if (l < 16)
                scp[((size_t)(z << 6) + (rowblk << 1) + wr) * BROWS +
                    cb + (wc << 6) + (nj << 4) + l] = s;
        }
    }

#pragma unroll
    for (int mi = 0; mi < 4; ++mi)
#pragma unroll
        for (int r = 0; r < 4; ++r) {
            float s = rsum[mi][r];
            s += __shfl_xor(s, 1); s += __shfl_xor(s, 2);
            s += __shfl_xor(s, 4); s += __shfl_xor(s, 8);
            if ((l & 15) == 0)
                srp[((size_t)(z << 4) + (colstrip << 1) + wc) * BROWS +
                    arow0 + (wr << 6) + (mi << 4) + ((l >> 4) << 2) + r] = s;
        }
}

// ---- fold partial strips + log-softmax diag + final loss (atomicAdd) ----
__global__ __launch_bounds__(256) void reduce_final(const float* __restrict__ srp,
                                                    const float* __restrict__ scp,
                                                    const float* __restrict__ diag,
                                                    float* __restrict__ out) {
    __shared__ float red[256];
    const int tid = threadIdx.x;
    const int idx = blockIdx.x * 256 + tid;   // 8192
    const int z = idx >> 12, row = idx & 4095;
    float a = 0.f, b = 0.f;
#pragma unroll 4
    for (int s = 0; s < 16; ++s) a += srp[((size_t)(z << 4) + s) * BROWS + row];
#pragma unroll 4
    for (int s = 0; s < 64; ++s) b += scp[((size_t)(z << 6) + s) * BROWS + row];
    // per (z,row): 2*diag_z - log(rowsum) - log(colsum); summed over z gives the
    // 4-matrix diagonal-logp sum
    red[tid] = 2.f * diag[(size_t)z * BROWS + row] - logf(a) - logf(b);
    __syncthreads();
    for (int s = 128; s > 0; s >>= 1) {
        if (tid < s) red[tid] += red[tid + s];
        __syncthreads();
    }
    if (tid == 0) atomicAdd(out, -red[0] / (4.0f * (float)BROWS));
}

extern "C" void kernel_launch(void* const* d_in, const int* in_sizes, int n_in,
                              void* d_out, int out_size, void* d_ws, size_t ws_size,
                              hipStream_t stream) {
    const float* f1 = (const float*)d_in[0];
    const float* f2 = (const float*)d_in[1];
    const float* W1 = (const float*)d_in[2];
    const float* b1 = (const float*)d_in[3];
    const float* W2 = (const float*)d_in[4];
    const float* b2 = (const float*)d_in[5];
    const float* queue = (const float*)d_in[6];
    float* out = (float*)d_out;

    char* ws = (char*)d_ws;
    unsigned char* qf8 = (unsigned char*)ws;                    // 8 MB
    unsigned char* pf8 = (unsigned char*)(ws + (8ull << 20));   // 2 MB
    unsigned char* nn8 = (unsigned char*)(ws + (10ull << 20));  // 2 MB
    u64_t* packed = (u64_t*)(ws + (12ull << 20));               // 64 KB
    float* diag   = (float*)(ws + (12ull << 20) + (64ull << 10));   // 32 KB
    float* srp    = (float*)(ws + (12ull << 20) + (96ull << 10));   // 512 KB
    float* scp    = (float*)(ws + (12ull << 20) + (608ull << 10));  // 2 MB

    // 1. conv(queue->fp8) + zero(packed) + projections, one launch
    prep<<<4096 + 512, 256, 0, stream>>>(queue, f1, f2, W1, b1, W2, b2,
                                         qf8, pf8, packed);
    // 2. fused lookup-GEMM + argmax
    nn_argmax8<<<512, 256, 0, stream>>>(pf8, qf8, packed);
    // 3. gather nn rows (+ zero out[0])
    gather8<<<256, 256, 0, stream>>>(packed, qf8, nn8, out);
    // 4. fused LSE GEMM (diag + exp row/col partial sums)
    lse_gemm8<<<512, 256, 0, stream>>>(nn8, pf8, srp, scp, diag);
    // 5. fold partials + loss
    reduce_final<<<32, 256, 0, stream>>>(srp, scp, diag, out);
}

// Round 20
// 155.926 us; speedup vs baseline: 1.8066x; 1.3618x over previous
//
#include <hip/hip_runtime.h>

typedef unsigned short ushort_t;
typedef unsigned long long u64_t;
typedef __attribute__((ext_vector_type(8))) unsigned char v8uc;
typedef __attribute__((ext_vector_type(8))) unsigned short v8us;
typedef __attribute__((ext_vector_type(8))) short v8bf;
typedef __attribute__((ext_vector_type(4))) float v4f;

#define BROWS 4096
#define DIMK 256
#define QN 32768
#define EXPSCALE 14.426950408889634f   // 10 * log2(e)

#if defined(__has_builtin)
#if __has_builtin(__builtin_amdgcn_cvt_pk_fp8_f32)
#define HAS_HW_FP8 1
#endif
#endif

__device__ __forceinline__ ushort_t f2bf(float f) {
    unsigned u = __float_as_uint(f);
    return (ushort_t)((u + 0x7FFFu + ((u >> 16) & 1u)) >> 16);   // RNE
}
__device__ __forceinline__ float bf2f(ushort_t u) {
    return __uint_as_float(((unsigned)u) << 16);
}
// f32 -> OCP e4m3fn, RNE (fallback path)
__device__ __forceinline__ unsigned char f2e4m3(float f) {
    unsigned u = __float_as_uint(f);
    unsigned s = (u >> 24) & 0x80u;
    int exp = (int)((u >> 23) & 0xFFu) - 127;
    unsigned man = u & 0x7FFFFFu;
    if (exp >= -6) {
        unsigned m = man >> 20;
        unsigned rest = man & 0xFFFFFu;
        if (rest > 0x80000u || (rest == 0x80000u && (m & 1u))) m++;
        if (m == 8u) { m = 0u; exp++; }
        if (exp > 8) return (unsigned char)(s | 0x7Eu);
        return (unsigned char)(s | ((unsigned)(exp + 7) << 3) | m);
    }
    if (exp < -10) return (unsigned char)s;
    unsigned full = man | 0x800000u;
    int shift = 20 + (-6 - exp);
    unsigned m = full >> shift;
    unsigned rest = full & ((1u << shift) - 1u);
    unsigned half = 1u << (shift - 1);
    if (rest > half || (rest == half && (m & 1u))) m++;
    if (m == 8u) return (unsigned char)(s | (1u << 3));
    return (unsigned char)(s | m);
}
// 8 floats -> 8 fp8 bytes (HW packed cvt when available)
__device__ __forceinline__ u64_t cvt8_fp8(const float* v) {
#ifdef HAS_HW_FP8
    int lo = 0, hi = 0;
    lo = __builtin_amdgcn_cvt_pk_fp8_f32(v[0], v[1], lo, false);
    lo = __builtin_amdgcn_cvt_pk_fp8_f32(v[2], v[3], lo, true);
    hi = __builtin_amdgcn_cvt_pk_fp8_f32(v[4], v[5], hi, false);
    hi = __builtin_amdgcn_cvt_pk_fp8_f32(v[6], v[7], hi, true);
    return ((u64_t)(unsigned)hi << 32) | (u64_t)(unsigned)lo;
#else
    u64_t r = 0;
#pragma unroll
    for (int q = 0; q < 8; ++q) r |= (u64_t)f2e4m3(v[q]) << (8 * q);
    return r;
#endif
}
__device__ __forceinline__ u64_t shfl_xor_u64(u64_t v, int off) {
    unsigned lo = (unsigned)(v & 0xFFFFFFFFull);
    unsigned hi = (unsigned)(v >> 32);
    lo = (unsigned)__shfl_xor((int)lo, off, 64);
    hi = (unsigned)__shfl_xor((int)hi, off, 64);
    return ((u64_t)hi << 32) | (u64_t)lo;
}
#define GLOAD(g, l_) __builtin_amdgcn_global_load_lds(                         \
    (const __attribute__((address_space(1))) void*)(g),                        \
    (__attribute__((address_space(3))) void*)(l_), 16, 0, 0)

// ==================== conv_all: queue->fp8, packed zero, F->bf16, W^T ====================
__global__ __launch_bounds__(256) void conv_all(const float* __restrict__ queue,
                                                const float* __restrict__ F1,
                                                const float* __restrict__ F2,
                                                const float* __restrict__ W1,
                                                const float* __restrict__ W2,
                                                unsigned char* __restrict__ qf8,
                                                ushort_t* __restrict__ Fb,
                                                ushort_t* __restrict__ WTb,
                                                u64_t* __restrict__ packed) {
    const int bid = blockIdx.x, j = threadIdx.x;
    if (bid < 4096) {
        if (bid < 32) packed[(bid << 8) + j] = 0ull;
        const size_t i = ((size_t)bid * 256 + j) * 8;
        float v[8];
        float4 x = *(const float4*)&queue[i];
        float4 y = *(const float4*)&queue[i + 4];
        v[0] = x.x; v[1] = x.y; v[2] = x.z; v[3] = x.w;
        v[4] = y.x; v[5] = y.y; v[6] = y.z; v[7] = y.w;
        const u64_t q = cvt8_fp8(v);
        const int row = (int)(i >> 8);
        const int col = (int)(i & 255);
        *(u64_t*)&qf8[((size_t)row << 8) + (col ^ ((((unsigned)row >> 3) & 1u) << 3))] = q;
        return;
    }
    if (bid < 5120) {
        // F1|F2 -> bf16 (plain row-major)
        const int idx = bid - 4096;                // 0..1023
        const int half = idx >> 9;
        const float* F = half ? F2 : F1;
        const size_t off = ((size_t)(idx & 511) * 256 + j) * 8;
        float4 x = *(const float4*)&F[off];
        float4 y = *(const float4*)&F[off + 4];
        v8us o;
        o[0] = f2bf(x.x); o[1] = f2bf(x.y); o[2] = f2bf(x.z); o[3] = f2bf(x.w);
        o[4] = f2bf(y.x); o[5] = f2bf(y.y); o[6] = f2bf(y.z); o[7] = f2bf(y.w);
        *(v8us*)&Fb[(size_t)half * BROWS * DIMK + off] = o;
        return;
    }
    // W^T build: 32 blocks; WTb[mtx][n][k] = W[mtx][k][n] in bf16
    const int s = bid - 5120;
    const int mtx = s >> 4;
    const int n0 = (s & 15) << 4;
    const float* Wsrc = mtx ? W2 : W1;
    float tmp[16];
#pragma unroll
    for (int r = 0; r < 16; ++r) tmp[r] = Wsrc[(size_t)j * 256 + n0 + r];
#pragma unroll
    for (int r = 0; r < 16; ++r)
        WTb[(size_t)mtx * 65536 + (size_t)(n0 + r) * 256 + j] = f2bf(tmp[r]);
}

// ==================== proj_mfma: 2-layer MLP + L2 norm -> fp8 ====================
// 256 blocks (2 halves x 128 row-blocks of 32), 256 thr = 4 waves (2Mr x 2Nc).
// A = F-tile [32][256] bf16 (swizzled stage); B = WT tile [128 n][64 k] per phase;
// h kept in LDS (A-layout swizzle); fused bias+relu; layer2; norm; fp8 store.
__global__ __launch_bounds__(256) void proj_mfma(const ushort_t* __restrict__ Fb,
                                                 const ushort_t* __restrict__ WTb,
                                                 const float* __restrict__ b1,
                                                 const float* __restrict__ b2,
                                                 unsigned char* __restrict__ pf8) {
    __shared__ __align__(16) ushort_t Fa[32 * 256];   // 16 KB: F, later p
    __shared__ __align__(16) ushort_t hb[32 * 256];   // 16 KB: h
    __shared__ __align__(16) ushort_t Bw[128 * 64];   // 16 KB: staged W^T tile
    __shared__ float sums[32][2];
    const int tid = threadIdx.x;
    const int w = tid >> 6, l = tid & 63;
    const int wr = w >> 1, wc = w & 1;
    const int lo = l >> 4;

    const int half = blockIdx.x >> 7;
    const int rb = blockIdx.x & 127;
    const int grow0 = (half << 12) + (rb << 5);   // row base in [8192]

    if (tid < 64) sums[tid >> 1][tid & 1] = 0.f;

    // stage Fa (source pre-swizzled: 16B slot s of row r holds octet (s&~7)|((s&7)^(r&7)))
#pragma unroll
    for (int j = 0; j < 4; ++j) {
        const int slot = (j << 8) + tid;
        const int row = slot >> 5, s = slot & 31;
        const int oct = (s & ~7) | ((s & 7) ^ (row & 7));
        GLOAD(&Fb[(size_t)(grow0 + row) * 256 + (oct << 3)],
              (ushort_t*)Fa + (((j << 8) + (w << 6)) << 3));
    }
    // NOTE: first in-loop __syncthreads drains this stage.

#pragma unroll
    for (int layer = 0; layer < 2; ++layer) {
        const ushort_t* WT = WTb + (size_t)layer * 65536;
        const ushort_t* Areg = layer ? hb : Fa;
        const float* bias = layer ? b2 : b1;
#pragma unroll
        for (int cp = 0; cp < 2; ++cp) {
            v4f acc[4];
#pragma unroll
            for (int n = 0; n < 4; ++n) acc[n] = (v4f){0.f, 0.f, 0.f, 0.f};
            for (int ph = 0; ph < 4; ++ph) {
                // stage WT tile [128 n][64 k] (octet swizzle m^(row&7))
#pragma unroll
                for (int j = 0; j < 4; ++j) {
                    const int slot = (j << 8) + tid;
                    const int row = slot >> 3, m = slot & 7;
                    const int ms = m ^ (row & 7);
                    GLOAD(&WT[(size_t)((cp << 7) + row) * 256 + (ph << 6) + (ms << 3)],
                          (ushort_t*)Bw + (((j << 8) + (w << 6)) << 3));
                }
                __syncthreads();
#pragma unroll
                for (int kk = 0; kk < 2; ++kk) {
                    const int k32 = (ph << 1) + kk;
                    const int arow = (wr << 4) + (l & 15);
                    const int aphys = ((k32 >> 1) << 3) |
                                      ((((k32 & 1) << 2) + lo) ^ (arow & 7));
                    v8bf av = *(const v8bf*)&Areg[(arow << 8) + (aphys << 3)];
#pragma unroll
                    for (int nj = 0; nj < 4; ++nj) {
                        const int brow = (wc << 6) + (nj << 4) + (l & 15);
                        const int bphys = ((kk << 2) + lo) ^ (brow & 7);
                        v8bf bv = *(const v8bf*)&Bw[(brow << 6) + (bphys << 3)];
                        acc[nj] = __builtin_amdgcn_mfma_f32_16x16x32_bf16(
                            av, bv, acc[nj], 0, 0, 0);
                    }
                }
                __syncthreads();   // all waves done with Bw
            }
            // epilogue: bias (+relu for layer0) -> write into hb (L0) / Fa (L1) + sumSq (L1)
#pragma unroll
            for (int nj = 0; nj < 4; ++nj) {
                const int col = (cp << 7) + (wc << 6) + (nj << 4) + (l & 15);
                const float bb = bias[col];
                const int o = col >> 3, q = col & 7;
                float sq[4];
#pragma unroll
                for (int r = 0; r < 4; ++r) {
                    const int row = (wr << 4) + (lo << 2) + r;
                    float v = acc[nj][r] + bb;
                    if (layer == 0) v = v > 0.f ? v : 0.f;
                    const int po = (o & ~7) | ((o & 7) ^ (row & 7));
                    if (layer == 0) hb[(row << 8) + (po << 3) + q] = f2bf(v);
                    else            Fa[(row << 8) + (po << 3) + q] = f2bf(v);
                    sq[r] = v * v;
                }
                if (layer == 1) {
#pragma unroll
                    for (int r = 0; r < 4; ++r) {
                        float s = sq[r];
                        s += __shfl_xor(s, 1); s += __shfl_xor(s, 2);
                        s += __shfl_xor(s, 4); s += __shfl_xor(s, 8);
                        if ((l & 15) == 0 && nj == 0) {}
                        sq[r] = s;
                    }
                }
                if (layer == 1 && (l & 15) == 0) {
#pragma unroll
                    for (int r = 0; r < 4; ++r)
                        if (nj == 0) {}   // accumulate below once per nj
                }
                if (layer == 1) {
                    // accumulate per-row partial (unique thread per (row,wc) per nj)
#pragma unroll
                    for (int r = 0; r < 4; ++r)
                        if ((l & 15) == 0)
                            sums[(wr << 4) + (lo << 2) + r][wc] += sq[r];
                }
            }
        }
        __syncthreads();   // h (or p) complete before next consumer
    }

    // norm + fp8 store (half-swapped global layout)
    const int row = tid >> 3;            // 32 rows
    const int cb = (tid & 7) << 5;       // 32 cols per thread
    const float tot = sums[row][0] + sums[row][1];
    const float inv = 1.f / fmaxf(sqrtf(tot), 1e-12f);
    const int prow = grow0 + row;
    const unsigned par = ((unsigned)prow >> 3) & 1u;
#pragma unroll
    for (int cc = 0; cc < 4; ++cc) {
        const int c0 = cb + (cc << 3);
        const int o = c0 >> 3;
        const int po = (o & ~7) | ((o & 7) ^ (row & 7));
        float v[8];
#pragma unroll
        for (int q = 0; q < 8; ++q)
            v[q] = bf2f(Fa[(row << 8) + (po << 3) + q]) * inv;
        *(u64_t*)&pf8[((size_t)prow << 8) + ((unsigned)c0 ^ (par << 3))] = cvt8_fp8(v);
    }
}

// ==================== shared fp8 GEMM shell (R17-proven, verbatim) ====================
__device__ __forceinline__ void stage_b8(const unsigned char* __restrict__ B, int col0,
                                         int kbyte, unsigned char* dst, int tid, int w) {
#pragma unroll
    for (int j = 0; j < 4; ++j) {
        const int slot = (j << 8) + tid;
        const int row = slot >> 3, m = slot & 7;
        const int ms = m ^ (row & 7);
        GLOAD(&B[(size_t)(col0 + row) * DIMK + kbyte + (ms << 4)],
              dst + (((j << 8) + (w << 6)) << 4));
    }
}
__device__ __forceinline__ void stage_a8(const unsigned char* __restrict__ A, int arow0,
                                         unsigned char* Alds, int tid, int w) {
#pragma unroll
    for (int j = 0; j < 8; ++j) {
        const int slot = (j << 8) + tid;
        const int row = slot >> 4, m = slot & 15;
        const int ms = m ^ (row & 15);
        GLOAD(&A[(size_t)(arow0 + row) * DIMK + (ms << 4)],
              Alds + (((j << 8) + (w << 6)) << 4));
    }
}

__global__ __launch_bounds__(256, 2) void nn_argmax8(const unsigned char* __restrict__ Pf8,
                                                     const unsigned char* __restrict__ Qf8,
                                                     u64_t* __restrict__ packed) {
    __shared__ __align__(16) unsigned char Alds[128 * 256];
    __shared__ __align__(16) unsigned char Bs[2][128 * 128];
    const int tid = threadIdx.x;
    const int w = tid >> 6, l = tid & 63;
    const int wr = w >> 1, wc = w & 1;

    const int bid = blockIdx.x;
    const int xcd = bid & 7, i = bid >> 3;
    const int half = xcd & 1;
    const int pairgrp = xcd >> 1;
    const int arow0 = (i & 31) << 7;
    const int colbase = (pairgrp << 13) + ((i >> 5) << 12);
    const unsigned char* A = Pf8 + (size_t)half * BROWS * DIMK;
    const unsigned char* B = Qf8;
    u64_t* pk_out = packed + (size_t)half * BROWS;

    stage_a8(A, arow0, Alds, tid, w);
    stage_b8(B, colbase, 0, &Bs[0][0], tid, w);
    __syncthreads();

    unsigned best[4][4];
#pragma unroll
    for (int a = 0; a < 4; ++a)
#pragma unroll
        for (int r = 0; r < 4; ++r) best[a][r] = 0u;

    for (int t = 0; t < 32; ++t) {
        v4f acc[4][4];
#pragma unroll
        for (int a = 0; a < 4; ++a)
#pragma unroll
            for (int b = 0; b < 4; ++b) acc[a][b] = (v4f){2.f, 2.f, 2.f, 2.f};

#pragma unroll
        for (int kh = 0; kh < 2; ++kh) {
            const int p = (t << 1) + kh;
            if (p + 1 < 64) {
                const int tn = (p + 1) >> 1, kn = (p + 1) & 1;
                stage_b8(B, colbase + (tn << 7), kn << 7, &Bs[(p + 1) & 1][0], tid, w);
            }
            const unsigned char* bufr = &Bs[p & 1][0];
#pragma unroll
            for (int c = 0; c < 4; ++c) {
                long av[4], bv[4];
#pragma unroll
                for (int mi = 0; mi < 4; ++mi) {
                    const int row = (wr << 6) + (mi << 4) + (l & 15);
                    const int o = (kh << 4) + (c << 2) + (l >> 4);
                    const int phys = (((o >> 1) ^ (row & 15)) << 4) +
                                     (((o ^ (row >> 3)) & 1) << 3);
                    av[mi] = *(const long*)&Alds[(row << 8) + phys];
                }
#pragma unroll
                for (int nj = 0; nj < 4; ++nj) {
                    const int row = (wc << 6) + (nj << 4) + (l & 15);
                    const int o = (c << 2) + (l >> 4);
                    const int phys = (((o >> 1) ^ (row & 7)) << 4) +
                                     (((o ^ (row >> 3)) & 1) << 3);
                    bv[nj] = *(const long*)&bufr[(row << 7) + phys];
                }
#pragma unroll
                for (int mi = 0; mi < 4; ++mi)
#pragma unroll
                    for (int nj = 0; nj < 4; ++nj)
                        acc[mi][nj] = __builtin_amdgcn_mfma_f32_16x16x32_fp8_fp8(
                            av[mi], bv[nj], acc[mi][nj], 0, 0, 0);
            }
            __syncthreads();
        }
#pragma unroll
        for (int mi = 0; mi < 4; ++mi)
#pragma unroll
            for (int r = 0; r < 4; ++r) {
                unsigned m = (__float_as_uint(acc[mi][0][r]) & 0xFFFFFF80u) |
                             ((unsigned)t << 2);
#pragma unroll
                for (int nj = 1; nj < 4; ++nj) {
                    unsigned c = (__float_as_uint(acc[mi][nj][r]) & 0xFFFFFF80u) |
                                 ((unsigned)t << 2) | (unsigned)nj;
                    m = c > m ? c : m;
                }
                if (m > best[mi][r]) best[mi][r] = m;
            }
    }

#pragma unroll
    for (int mi = 0; mi < 4; ++mi)
#pragma unroll
        for (int r = 0; r < 4; ++r) {
            const unsigned wb = best[mi][r];
            const unsigned col = (unsigned)(colbase + (int)(((wb >> 2) & 31u) << 7) +
                                            (wc << 6) + (int)((wb & 3u) << 4)) + (l & 15);
            u64_t pk = ((u64_t)wb << 32) | (u64_t)(0xFFFFFFFFu - col);
#pragma unroll
            for (int off = 1; off < 16; off <<= 1) {
                u64_t o = shfl_xor_u64(pk, off);
                if (o > pk) pk = o;
            }
            if ((l & 15) == 0)
                atomicMax(&pk_out[arow0 + (wr << 6) + (mi << 4) + ((l >> 4) << 2) + r], pk);
        }
}

__global__ __launch_bounds__(256) void gather8(const u64_t* __restrict__ packed,
                                               const unsigned char* __restrict__ qf8,
                                               unsigned char* __restrict__ nn8,
                                               float* __restrict__ out) {
    if (blockIdx.x == 0 && threadIdx.x == 0) out[0] = 0.f;
    const int r8 = threadIdx.x >> 5;
    const int c = threadIdx.x & 31;
    for (int base = blockIdx.x * 8; base < 2 * BROWS; base += (int)gridDim.x * 8) {
        const int i = base + r8;
        const unsigned idx = 0xFFFFFFFFu - (unsigned)(packed[i] & 0xFFFFFFFFull);
        const unsigned sp = (idx >> 3) & 1u;
        const unsigned dp = (((unsigned)i) >> 3) & 1u;
        *(u64_t*)&nn8[((size_t)i << 8) + ((unsigned)(c << 3) ^ (dp << 3))] =
            *(const u64_t*)&qf8[((size_t)idx << 8) + ((unsigned)(c << 3) ^ (sp << 3))];
    }
}

__global__ __launch_bounds__(256, 2) void lse_gemm8(const unsigned char* __restrict__ nn8,
                                                    const unsigned char* __restrict__ pf8,
                                                    float* __restrict__ srp,
                                                    float* __restrict__ scp,
                                                    float* __restrict__ diag) {
    __shared__ __align__(16) unsigned char Alds[128 * 256];
    __shared__ __align__(16) unsigned char Bs[2][128 * 128];
    const int tid = threadIdx.x;
    const int w = tid >> 6, l = tid & 63;
    const int wr = w >> 1, wc = w & 1;

    const int z = blockIdx.x >> 8;
    const int i = blockIdx.x & 255;
    const int rowblk = i & 31;
    const int colstrip = i >> 5;
    const int arow0 = rowblk << 7;
    const int colbase = colstrip << 9;
    const unsigned char* A = nn8 + (size_t)z * BROWS * DIMK;
    const unsigned char* B = pf8 + (size_t)(1 - z) * BROWS * DIMK;
    float* dg = diag + (size_t)z * BROWS;

    stage_a8(A, arow0, Alds, tid, w);
    stage_b8(B, colbase, 0, &Bs[0][0], tid, w);
    __syncthreads();

    float rsum[4][4];
#pragma unroll
    for (int a = 0; a < 4; ++a)
#pragma unroll
        for (int r = 0; r < 4; ++r) rsum[a][r] = 0.f;

    for (int t = 0; t < 4; ++t) {
        v4f acc[4][4];
#pragma unroll
        for (int a = 0; a < 4; ++a)
#pragma unroll
            for (int b = 0; b < 4; ++b) acc[a][b] = (v4f){0.f, 0.f, 0.f, 0.f};

#pragma unroll
        for (int kh = 0; kh < 2; ++kh) {
            const int p = (t << 1) + kh;
            if (p + 1 < 8) {
                const int tn = (p + 1) >> 1, kn = (p + 1) & 1;
                stage_b8(B, colbase + (tn << 7), kn << 7, &Bs[(p + 1) & 1][0], tid, w);
            }
            const unsigned char* bufr = &Bs[p & 1][0];
#pragma unroll
            for (int c = 0; c < 4; ++c) {
                long av[4], bv[4];
#pragma unroll
                for (int mi = 0; mi < 4; ++mi) {
                    const int row = (wr << 6) + (mi << 4) + (l & 15);
                    const int o = (kh << 4) + (c << 2) + (l >> 4);
                    const int phys = (((o >> 1) ^ (row & 15)) << 4) +
                                     (((o ^ (row >> 3)) & 1) << 3);
                    av[mi] = *(const long*)&Alds[(row << 8) + phys];
                }
#pragma unroll
                for (int nj = 0; nj < 4; ++nj) {
                    const int row = (wc << 6) + (nj << 4) + (l & 15);
                    const int o = (c << 2) + (l >> 4);
                    const int phys = (((o >> 1) ^ (row & 7)) << 4) +
                                     (((o ^ (row >> 3)) & 1) << 3);
                    bv[nj] = *(const long*)&bufr[(row << 7) + phys];
                }
#pragma unroll
                for (int mi = 0; mi < 4; ++mi)
#pragma unroll
                    for (int nj = 0; nj < 4; ++nj)
                        acc[mi][nj] = __builtin_amdgcn_mfma_f32_16x16x32_fp8_fp8(
                            av[mi], bv[nj], acc[mi][nj], 0, 0, 0);
            }
            __syncthreads();
        }

        const int cb = colbase + (t << 7);
#pragma unroll
        for (int mi = 0; mi < 4; ++mi)
#pragma unroll
            for (int nj = 0; nj < 4; ++nj) {
                const int gr16 = arow0 + (wr << 6) + (mi << 4);
                const int gc16 = cb + (wc << 6) + (nj << 4);
                if (gr16 == gc16) {
#pragma unroll
                    for (int r = 0; r < 4; ++r) {
                        const int rr = ((l >> 4) << 2) + r;
                        if ((l & 15) == rr) dg[gr16 + rr] = acc[mi][nj][r] * 10.0f;
                    }
                }
            }
#pragma unroll
        for (int mi = 0; mi < 4; ++mi)
#pragma unroll
            for (int nj = 0; nj < 4; ++nj) {
                v4f tv = acc[mi][nj];
                tv[0] = exp2f(tv[0] * EXPSCALE);
                tv[1] = exp2f(tv[1] * EXPSCALE);
                tv[2] = exp2f(tv[2] * EXPSCALE);
                tv[3] = exp2f(tv[3] * EXPSCALE);
                acc[mi][nj] = tv;
            }
#pragma unroll
        for (int mi = 0; mi < 4; ++mi)
#pragma unroll
            for (int r = 0; r < 4; ++r) {
                float s = 0.f;
#pragma unroll
                for (int nj = 0; nj < 4; ++nj) s += acc[mi][nj][r];
                rsum[mi][r] += s;
            }
#pragma unroll
        for (int nj = 0; nj < 4; ++nj) {
            float s = 0.f;
#pragma unroll
            for (int mi = 0; mi < 4; ++mi)
#pragma unroll
                for (int r = 0; r < 4; ++r) s += acc[mi][nj][r];
            s += __shfl_xor(s, 16); s += __shfl_xor(s, 32);
            if (l < 16)
                scp[((size_t)(z << 6) + (rowblk << 1) + wr) * BROWS +
                    cb + (wc << 6) + (nj << 4) + l] = s;
        }
    }

#pragma unroll
    for (int mi = 0; mi < 4; ++mi)
#pragma unroll
        for (int r = 0; r < 4; ++r) {
            float s = rsum[mi][r];
            s += __shfl_xor(s, 1); s += __shfl_xor(s, 2);
            s += __shfl_xor(s, 4); s += __shfl_xor(s, 8);
            if ((l & 15) == 0)
                srp[((size_t)(z << 4) + (colstrip << 1) + wc) * BROWS +
                    arow0 + (wr << 6) + (mi << 4) + ((l >> 4) << 2) + r] = s;
        }
}

__global__ __launch_bounds__(256) void reduce_final(const float* __restrict__ srp,
                                                    const float* __restrict__ scp,
                                                    const float* __restrict__ diag,
                                                    float* __restrict__ out) {
    __shared__ float red[256];
    const int tid = threadIdx.x;
    const int idx = blockIdx.x * 256 + tid;
    const int z = idx >> 12, row = idx & 4095;
    float a = 0.f, b = 0.f;
#pragma unroll 4
    for (int s = 0; s < 16; ++s) a += srp[((size_t)(z << 4) + s) * BROWS + row];
#pragma unroll 4
    for (int s = 0; s < 64; ++s) b += scp[((size_t)(z << 6) + s) * BROWS + row];
    red[tid] = 2.f * diag[(size_t)z * BROWS + row] - logf(a) - logf(b);
    __syncthreads();
    for (int s = 128; s > 0; s >>= 1) {
        if (tid < s) red[tid] += red[tid + s];
        __syncthreads();
    }
    if (tid == 0) atomicAdd(out, -red[0] / (4.0f * (float)BROWS));
}

extern "C" void kernel_launch(void* const* d_in, const int* in_sizes, int n_in,
                              void* d_out, int out_size, void* d_ws, size_t ws_size,
                              hipStream_t stream) {
    const float* f1 = (const float*)d_in[0];
    const float* f2 = (const float*)d_in[1];
    const float* W1 = (const float*)d_in[2];
    const float* b1 = (const float*)d_in[3];
    const float* W2 = (const float*)d_in[4];
    const float* b2 = (const float*)d_in[5];
    const float* queue = (const float*)d_in[6];
    float* out = (float*)d_out;

    char* ws = (char*)d_ws;
    unsigned char* qf8 = (unsigned char*)ws;                    // 8 MB
    unsigned char* pf8 = (unsigned char*)(ws + (8ull << 20));   // 2 MB
    unsigned char* nn8 = (unsigned char*)(ws + (10ull << 20));  // 2 MB
    u64_t* packed = (u64_t*)(ws + (12ull << 20));               // 64 KB
    float* diag   = (float*)(ws + (12ull << 20) + (64ull << 10));   // 32 KB
    float* srp    = (float*)(ws + (12ull << 20) + (96ull << 10));   // 512 KB
    float* scp    = (float*)(ws + (12ull << 20) + (608ull << 10));  // 2 MB
    ushort_t* Fb  = (ushort_t*)(ws + (16ull << 20));            // 4 MB
    ushort_t* WTb = (ushort_t*)(ws + (20ull << 20));            // 256 KB

    // 1. queue->fp8 + packed-zero + F->bf16 + W^T build
    conv_all<<<5152, 256, 0, stream>>>(queue, f1, f2, W1, W2, qf8, Fb, WTb, packed);
    // 2. MFMA projection (2 layers + norm) -> fp8
    proj_mfma<<<256, 256, 0, stream>>>(Fb, WTb, b1, b2, pf8);
    // 3. fused lookup-GEMM + argmax
    nn_argmax8<<<512, 256, 0, stream>>>(pf8, qf8, packed);
    // 4. gather nn rows (+ zero out[0])
    gather8<<<256, 256, 0, stream>>>(packed, qf8, nn8, out);
    // 5. fused LSE GEMM
    lse_gemm8<<<512, 256, 0, stream>>>(nn8, pf8, srp, scp, diag);
    // 6. fold partials + loss
    reduce_final<<<32, 256, 0, stream>>>(srp, scp, diag, out);
}